// Round 7
// baseline (195.591 us; speedup 1.0000x reference)
//
#include <hip/hip_runtime.h>
#include <hip/hip_bf16.h>
#include <math.h>

#define N_NODES 50000
#define N_EDGES 800000
#define F_DIM 128
#define H_DIM 64
#define IN_DIM 129   // F_DIM + 1 (binary feature)
#define ETOT (N_EDGES + N_NODES)          // 850000 CSR entries
#define PROJ_BLKS ((N_NODES + 31) / 32)   // 1563 (32 nodes/block)
#define OUT_BLKS  ((N_NODES + 31) / 32)   // 1563
#define NB 196                            // node buckets (256 nodes each; last has 80)
#define CAP 6144                          // csr LDS capacity (mean 4096, sigma 64)
#define EPB 3125                          // edges per bucket block (256 blocks exact)
#define BKT_BLKS 256

typedef __hip_bfloat16 bf16;
typedef __attribute__((ext_vector_type(8))) short bf16x8;   // MFMA A/B frag (4 VGPR)
typedef __attribute__((ext_vector_type(4))) float f32x4;    // MFMA C/D frag

static __device__ __forceinline__ float bs2f(short s) {
    union { float f; unsigned u; } c; c.u = ((unsigned)(unsigned short)s) << 16; return c.f;
}
static __device__ __forceinline__ short f2bs(float f) {
    union { bf16 b; short s; } u; u.b = __float2bfloat16(f); return u.s;
}

// ---------------------------------------------------------------------------
// Prep: pack W (proj) and Wo (out) hi/lo MFMA B-fragments once, zero gtot.
// ---------------------------------------------------------------------------
__global__ __launch_bounds__(256) void prep_kernel(
    const float* __restrict__ Wl, const float* __restrict__ Wr,
    const float* __restrict__ Wo,
    bf16* __restrict__ whi, bf16* __restrict__ wlo,
    bf16* __restrict__ wohi, bf16* __restrict__ wolo,
    int* __restrict__ gtot)
{
    int b = blockIdx.x, t = threadIdx.x;
    if (b < 8) {                              // [Wl;Wr] frags: 2048 slots
        int s = b * 256 + t;
        int fid = s >> 6, l = s & 63;
        int wave = fid >> 3, nt = (fid >> 2) & 1, ks = fid & 3;
        int ch = wave * 32 + nt * 16 + (l & 15);
        int kb = ks * 32 + (l >> 4) * 8;
        const float* wrow = (ch < 64) ? Wl + (size_t)ch * IN_DIM
                                      : Wr + (size_t)(ch - 64) * IN_DIM;
        #pragma unroll
        for (int j = 0; j < 8; ++j) {
            float v = wrow[kb + j];
            short hs = f2bs(v);
            short ls = f2bs(v - bs2f(hs));
            ((short*)whi)[(size_t)s * 8 + j] = hs;
            ((short*)wlo)[(size_t)s * 8 + j] = ls;
        }
    } else if (b < 12) {                      // Wo frags: 1024 slots
        int s = (b - 8) * 256 + t;
        int fid = s >> 6, l = s & 63;
        int wave = fid >> 2, nt = (fid >> 1) & 1, ks = fid & 1;
        int ch = wave * 32 + nt * 16 + (l & 15);
        int kb = ks * 32 + (l >> 4) * 8;
        const float* wrow = Wo + (size_t)ch * H_DIM;
        #pragma unroll
        for (int j = 0; j < 8; ++j) {
            float v = wrow[kb + j];
            short hs = f2bs(v);
            short ls = f2bs(v - bs2f(hs));
            ((short*)wohi)[(size_t)s * 8 + j] = hs;
            ((short*)wolo)[(size_t)s * 8 + j] = ls;
        }
    } else {                                  // zero bucket totals
        if (t < NB) gtot[t] = 0;
    }
}

// ---------------------------------------------------------------------------
// K-bucket: level 1, atomic-free placement (standalone — split from the R5/R6
// hybrid; the merge bought nothing and muddied occupancy/attribution).
// 3125 edges register-staged (13/thread), 196-bin LDS histogram + LDS scan ->
// per-block-private scatter into bstore2[b*3125+..] grouped by bucket;
// publishes (base,count) in bofsT and non-returning gtot adds.
// ---------------------------------------------------------------------------
__global__ __launch_bounds__(256) void bucket_kernel(
    const int* __restrict__ esrc, const int* __restrict__ edst,
    int* __restrict__ gtot, unsigned* __restrict__ bstore2,
    int* __restrict__ bofsT)
{
    __shared__ int smem[1024];   // hist 196 | base 196 | cur 196 | scan 256
    int* hist = smem;
    int* base = smem + 256;
    int* cur  = smem + 512;
    int* shs  = smem + 768;
    int t = threadIdx.x;
    int b = blockIdx.x;
    int e0 = b * EPB;
    if (t < NB) hist[t] = 0;
    __syncthreads();

    int myd[13]; int mys[13];
    #pragma unroll
    for (int i = 0; i < 13; ++i) {       // 3125 = 12*256 + 53
        int k = t + i * 256;
        bool v = k < EPB;
        int dst = v ? edst[e0 + k] : -1;
        int sc  = v ? esrc[e0 + k] : 0;
        myd[i] = dst; mys[i] = sc;
        if (v) atomicAdd(&hist[dst >> 8], 1);     // LDS atomic
    }
    __syncthreads();

    int hv = (t < NB) ? hist[t] : 0;
    shs[t] = hv;
    __syncthreads();
    #pragma unroll
    for (int d = 1; d < 256; d <<= 1) {
        int x = (t >= d) ? shs[t - d] : 0;
        __syncthreads();
        shs[t] += x;
        __syncthreads();
    }
    if (t < NB) {
        int bs = shs[t] - hv;
        base[t] = bs;
        cur[t] = 0;
        if (hv) atomicAdd(&gtot[t], hv);          // non-returning global
        bofsT[t * 256 + b] = (bs << 16) | hv;     // packed (base,count)
    }
    __syncthreads();

    #pragma unroll
    for (int i = 0; i < 13; ++i) {
        if (myd[i] >= 0) {
            int j = myd[i] >> 8;
            int slot = base[j] + atomicAdd(&cur[j], 1);   // LDS atomic
            bstore2[(size_t)e0 + slot] =
                ((unsigned)myd[i] << 16) | (unsigned)mys[i];
        }
    }
}

// ---------------------------------------------------------------------------
// Proj (MFMA): [xl|xr] = x @ [Wl;Wr]^T + bias. 32 nodes/block; B-frags
// loaded coalesced from the prep pack; epilogue staged through an
// XOR-swizzled LDS tile so global stores are coalesced bf16x8.
// ---------------------------------------------------------------------------
__global__ __launch_bounds__(256) void proj_mfma(
    const float* __restrict__ xf, const float* __restrict__ xb,
    const float* __restrict__ Wl, const float* __restrict__ bl,
    const float* __restrict__ Wr, const float* __restrict__ br,
    const bf16* __restrict__ whi, const bf16* __restrict__ wlo,
    bf16* __restrict__ xl, bf16* __restrict__ xr)
{
    __shared__ short lds[32 * 128];   // [node_local][ch], 16B chunks XOR-swizzled

    int wave = threadIdx.x >> 6;
    int lane = threadIdx.x & 63;
    int n = lane & 15, q = lane >> 4;
    int node0 = blockIdx.x * 32;

    bf16x8 bhi[2][4], blo_[2][4];
    float biasv[2], w128[2];
    #pragma unroll
    for (int nt = 0; nt < 2; ++nt) {
        int ch = wave * 32 + nt * 16 + n;
        #pragma unroll
        for (int ks = 0; ks < 4; ++ks) {
            int fid = wave * 8 + nt * 4 + ks;
            bhi[nt][ks]  = *(const bf16x8*)(whi + ((size_t)fid * 64 + lane) * 8);
            blo_[nt][ks] = *(const bf16x8*)(wlo + ((size_t)fid * 64 + lane) * 8);
        }
        biasv[nt] = (ch < 64) ? bl[ch] : br[ch - 64];
        w128[nt]  = (ch < 64) ? Wl[(size_t)ch * IN_DIM + 128]
                              : Wr[(size_t)(ch - 64) * IN_DIM + 128];
    }

    #pragma unroll
    for (int mt = 0; mt < 2; ++mt) {
        int nb = node0 + mt * 16;
        if (nb < N_NODES) {
            const float* xrow = xf + (size_t)(nb + n) * F_DIM;
            bf16x8 a[4];
            #pragma unroll
            for (int ks = 0; ks < 4; ++ks) {
                float4 u = *(const float4*)(xrow + ks * 32 + q * 8);
                float4 v = *(const float4*)(xrow + ks * 32 + q * 8 + 4);
                bf16x8 tt;
                tt[0] = f2bs(u.x); tt[1] = f2bs(u.y); tt[2] = f2bs(u.z); tt[3] = f2bs(u.w);
                tt[4] = f2bs(v.x); tt[5] = f2bs(v.y); tt[6] = f2bs(v.z); tt[7] = f2bs(v.w);
                a[ks] = tt;
            }
            f32x4 acc[2] = {{0.f,0.f,0.f,0.f},{0.f,0.f,0.f,0.f}};
            #pragma unroll
            for (int ks = 0; ks < 4; ++ks) {
                #pragma unroll
                for (int nt = 0; nt < 2; ++nt) {
                    acc[nt] = __builtin_amdgcn_mfma_f32_16x16x32_bf16(a[ks], bhi[nt][ks],  acc[nt], 0, 0, 0);
                    acc[nt] = __builtin_amdgcn_mfma_f32_16x16x32_bf16(a[ks], blo_[nt][ks], acc[nt], 0, 0, 0);
                }
            }
            float4 xbv = *(const float4*)(xb + nb + q * 4);
            float xbr[4] = {xbv.x, xbv.y, xbv.z, xbv.w};
            #pragma unroll
            for (int nt = 0; nt < 2; ++nt) {
                int ch = wave * 32 + nt * 16 + n;
                int blk = ch >> 3, pos = ch & 7;
                #pragma unroll
                for (int r = 0; r < 4; ++r) {
                    int nodeL = mt * 16 + q * 4 + r;   // C/D: row = quad*4 + reg
                    float val = acc[nt][r] + xbr[r] * w128[nt] + biasv[nt];
                    lds[nodeL * 128 + ((blk ^ (nodeL & 7)) << 3) + pos] = f2bs(val);
                }
            }
        }
    }
    __syncthreads();

    // Coalesced write-back: thread t -> node t>>3, 16B chunk t&7 of xl and xr.
    int nl = threadIdx.x >> 3, bk = threadIdx.x & 7;
    int node = node0 + nl;
    if (node < N_NODES) {
        bf16x8 v0 = *(const bf16x8*)(lds + nl * 128 + ((bk ^ (nl & 7)) << 3));
        *(bf16x8*)(xl + (size_t)node * H_DIM + bk * 8) = v0;
        bf16x8 v1 = *(const bf16x8*)(lds + nl * 128 + (((8 + bk) ^ (nl & 7)) << 3));
        *(bf16x8*)(xr + (size_t)node * H_DIM + bk * 8) = v1;
    }
}

// ---------------------------------------------------------------------------
// K-csr: level 2, 512 thr/block, one block per bucket. Gathers the bucket's
// slices from the 256 per-block regions, then 256-bin LDS histogram by
// dst&255, LDS scans -> offs[] (self-loop at segment head) and final CSR.
// ---------------------------------------------------------------------------
__global__ __launch_bounds__(512) void csr_kernel(
    const int* __restrict__ gtot, const unsigned* __restrict__ bstore2,
    const int* __restrict__ bofsT,
    int* __restrict__ offs, int* __restrict__ csr_src)
{
    __shared__ unsigned ent[CAP];
    __shared__ int sh[256], gb_[256], bcnt_[256], bbase_[256];
    __shared__ int h256[256], start[256], c2[256];
    __shared__ int bb_s, C_s;
    int j = blockIdx.x, t = threadIdx.x;

    // per-source-block info + scan of counts -> gather bases
    int bcnt = 0;
    if (t < 256) {
        unsigned v = (unsigned)bofsT[j * 256 + t];
        bbase_[t] = (int)(v >> 16);
        bcnt = (int)(v & 0xffffu);
        bcnt_[t] = bcnt;
        sh[t] = bcnt;
    }
    __syncthreads();
    #pragma unroll
    for (int d = 1; d < 256; d <<= 1) {
        int x = (t >= d && t < 256) ? sh[t - d] : 0;
        __syncthreads();
        if (t < 256) sh[t] += x;
        __syncthreads();
    }
    if (t < 256) gb_[t] = sh[t] - bcnt;
    if (t == 255) C_s = sh[255];
    __syncthreads();
    int C = C_s;

    // gather this bucket's entries into LDS
    if (t < 256) {
        const unsigned* p = bstore2 + (size_t)t * EPB + bbase_[t];
        int o = gb_[t];
        int c = bcnt_[t];
        for (int i = 0; i < c; ++i) ent[o + i] = p[i];
    }
    __syncthreads();

    // bucket-base prefix: val_j' = gtot[j'] + (real nodes in bucket j')
    int val = 0;
    if (t < NB) val = gtot[t] + ((t < NB - 1) ? 256 : (N_NODES - (NB - 1) * 256));
    if (t < 256) sh[t] = val;
    __syncthreads();
    #pragma unroll
    for (int d = 1; d < 256; d <<= 1) {
        int x = (t >= d && t < 256) ? sh[t - d] : 0;
        __syncthreads();
        if (t < 256) sh[t] += x;
        __syncthreads();
    }
    if (t == j) bb_s = sh[t] - val;        // exclusive prefix at own bucket
    if (t < 256) h256[t] = 0;
    __syncthreads();
    int bb = bb_s;

    // 256-bin histogram over entries
    for (int k = t; k < C; k += 512)
        atomicAdd(&h256[(ent[k] >> 16) & 255], 1);   // LDS atomic
    __syncthreads();

    // scan of per-node widths (deg + 1 self-loop for real nodes)
    int w = 0;
    if (t < 256) {
        w = h256[t] + ((j * 256 + t < N_NODES) ? 1 : 0);
        sh[t] = w;
    }
    __syncthreads();
    #pragma unroll
    for (int d = 1; d < 256; d <<= 1) {
        int x = (t >= d && t < 256) ? sh[t - d] : 0;
        __syncthreads();
        if (t < 256) sh[t] += x;
        __syncthreads();
    }
    if (t < 256) {
        int st = bb + sh[t] - w;
        start[t] = st;
        c2[t] = 0;
        int node = j * 256 + t;
        if (node < N_NODES) {
            offs[node] = st;
            csr_src[st] = node;             // self-loop at segment head
        }
    }
    if (j == NB - 1 && t == 0) offs[N_NODES] = ETOT;   // sentinel
    __syncthreads();

    for (int k = t; k < C; k += 512) {
        unsigned en = ent[k];
        int bin = (en >> 16) & 255;
        int r = atomicAdd(&c2[bin], 1);     // LDS atomic
        csr_src[start[bin] + 1 + r] = (int)(en & 0xffffu);
    }
}

// ---------------------------------------------------------------------------
// K2b (fused score + aggregate, wave-per-dst). Depth-5 row / depth-7 index
// gather pipeline (named registers, explicit rotation — runtime-indexed
// arrays would spill to scratch). Random 128B gathers from L3 are the
// latency wall; 4 rows in flight per wave ~doubles MLP vs the old depth-2.
// ---------------------------------------------------------------------------
__global__ __launch_bounds__(256) void agg_fused(
    const int* __restrict__ csr_src, const int* __restrict__ offs,
    const bf16* __restrict__ xl, const bf16* __restrict__ xr,
    const float* __restrict__ att, const float* __restrict__ gb,
    bf16* __restrict__ h)
{
    int wid  = (blockIdx.x * 256 + threadIdx.x) >> 6;   // dst node
    int lane = threadIdx.x & 63;
    if (wid >= N_NODES) return;
    int g  = lane >> 3;   // edge slot within batch
    int c8 = lane & 7;    // channel octet

    float attv[8], xrv[8];
    {
        bf16x8 xrow = *(const bf16x8*)(xr + (size_t)wid * H_DIM + c8 * 8);
        float4 a0 = *(const float4*)(att + c8 * 8);
        float4 a1 = *(const float4*)(att + c8 * 8 + 4);
        attv[0] = a0.x; attv[1] = a0.y; attv[2] = a0.z; attv[3] = a0.w;
        attv[4] = a1.x; attv[5] = a1.y; attv[6] = a1.z; attv[7] = a1.w;
        #pragma unroll
        for (int j = 0; j < 8; ++j) xrv[j] = bs2f(xrow[j]);
    }

    int beg = offs[wid];
    int end = offs[wid + 1];          // >= beg+1 (self-loop)
    int last = end - 1;

    #define CLMP(x) (((x) < end) ? (x) : last)

    // prologue: 7 indices + 4 rows issued up-front (independent burst)
    int j0 = csr_src[CLMP(beg + g)];
    int j1 = csr_src[CLMP(beg + 8 + g)];
    int j2 = csr_src[CLMP(beg + 16 + g)];
    int j3 = csr_src[CLMP(beg + 24 + g)];
    int s4 = csr_src[CLMP(beg + 32 + g)];
    int s5 = csr_src[CLMP(beg + 40 + g)];
    int s6 = csr_src[CLMP(beg + 48 + g)];
    bf16x8 r0 = *(const bf16x8*)(xl + (size_t)j0 * H_DIM + c8 * 8);
    bf16x8 r1 = *(const bf16x8*)(xl + (size_t)j1 * H_DIM + c8 * 8);
    bf16x8 r2 = *(const bf16x8*)(xl + (size_t)j2 * H_DIM + c8 * 8);
    bf16x8 r3 = *(const bf16x8*)(xl + (size_t)j3 * H_DIM + c8 * 8);

    float den = 0.f;
    float acc[8] = {0.f, 0.f, 0.f, 0.f, 0.f, 0.f, 0.f, 0.f};

    for (int base = beg; base < end; base += 8) {
        int s7 = csr_src[CLMP(base + 56 + g)];                    // idx batch+7
        bf16x8 r4 = *(const bf16x8*)(xl + (size_t)s4 * H_DIM + c8 * 8); // row b+4

        bool valid = (base + g) < end;
        float xv[8], p = 0.f;
        #pragma unroll
        for (int j = 0; j < 8; ++j) {
            xv[j] = bs2f(r0[j]);
            float m = xv[j] + xrv[j];
            m = (m > 0.f) ? m : 0.2f * m;
            p += m * attv[j];
        }
        p += __shfl_xor(p, 1);
        p += __shfl_xor(p, 2);
        p += __shfl_xor(p, 4);      // all lanes of group g now hold p_g
        float ex = valid ? __expf(p) : 0.f;
        den += ex;
        #pragma unroll
        for (int j = 0; j < 8; ++j) acc[j] += ex * xv[j];

        r0 = r1; r1 = r2; r2 = r3; r3 = r4;
        s4 = s5; s5 = s6; s6 = s7;
    }
    #undef CLMP

    // combine the 8 edge-groups (once per dst)
    #pragma unroll
    for (int j = 0; j < 8; ++j) {
        acc[j] += __shfl_xor(acc[j], 8);
        acc[j] += __shfl_xor(acc[j], 16);
        acc[j] += __shfl_xor(acc[j], 32);
    }
    den += __shfl_xor(den, 8);
    den += __shfl_xor(den, 16);
    den += __shfl_xor(den, 32);

    if (g == 0) {
        float inv = 1.0f / den;
        float4 g0 = *(const float4*)(gb + c8 * 8);
        float4 g1 = *(const float4*)(gb + c8 * 8 + 4);
        float gbv[8] = {g0.x, g0.y, g0.z, g0.w, g1.x, g1.y, g1.z, g1.w};
        bf16x8 ov;
        #pragma unroll
        for (int j = 0; j < 8; ++j) {
            float v = acc[j] * inv + gbv[j];
            v = (v > 0.f) ? v : expm1f(v);
            ov[j] = f2bs(v);
        }
        *(bf16x8*)(h + (size_t)wid * H_DIM + c8 * 8) = ov;
    }
}

// ---------------------------------------------------------------------------
// K3 (MFMA): logits = h @ Wo^T + bo (+ softplus(dispersion) tail on block 0).
// ---------------------------------------------------------------------------
__global__ __launch_bounds__(256) void out_mfma(
    const bf16* __restrict__ h,
    const bf16* __restrict__ wohi, const bf16* __restrict__ wolo,
    const float* __restrict__ bo, const float* __restrict__ disp,
    float* __restrict__ out)
{
    if (blockIdx.x == 0 && threadIdx.x < F_DIM) {
        float d = disp[threadIdx.x];
        out[(size_t)N_NODES * F_DIM + threadIdx.x] = (d > 20.f) ? d : log1pf(__expf(d));
    }

    __shared__ float ldso[32 * 132];   // +4 f32 row pad -> bank spread

    int wave = threadIdx.x >> 6;
    int lane = threadIdx.x & 63;
    int n = lane & 15, q = lane >> 4;
    int node0 = blockIdx.x * 32;

    bf16x8 bhi[2][2], blo_[2][2];
    float bov[2];
    #pragma unroll
    for (int nt = 0; nt < 2; ++nt) {
        int ch = wave * 32 + nt * 16 + n;
        #pragma unroll
        for (int ks = 0; ks < 2; ++ks) {
            int fid = wave * 4 + nt * 2 + ks;
            bhi[nt][ks]  = *(const bf16x8*)(wohi + ((size_t)fid * 64 + lane) * 8);
            blo_[nt][ks] = *(const bf16x8*)(wolo + ((size_t)fid * 64 + lane) * 8);
        }
        bov[nt] = bo[ch];
    }

    #pragma unroll
    for (int mt = 0; mt < 2; ++mt) {
        int nb = node0 + mt * 16;
        if (nb < N_NODES) {
            const bf16* hrow = h + (size_t)(nb + n) * H_DIM;
            bf16x8 a[2];
            #pragma unroll
            for (int ks = 0; ks < 2; ++ks)
                a[ks] = *(const bf16x8*)(hrow + ks * 32 + q * 8);
            f32x4 acc[2] = {{0.f,0.f,0.f,0.f},{0.f,0.f,0.f,0.f}};
            #pragma unroll
            for (int ks = 0; ks < 2; ++ks) {
                #pragma unroll
                for (int nt = 0; nt < 2; ++nt) {
                    acc[nt] = __builtin_amdgcn_mfma_f32_16x16x32_bf16(a[ks], bhi[nt][ks],  acc[nt], 0, 0, 0);
                    acc[nt] = __builtin_amdgcn_mfma_f32_16x16x32_bf16(a[ks], blo_[nt][ks], acc[nt], 0, 0, 0);
                }
            }
            #pragma unroll
            for (int nt = 0; nt < 2; ++nt) {
                int ch = wave * 32 + nt * 16 + n;
                #pragma unroll
                for (int r = 0; r < 4; ++r) {
                    int nodeL = mt * 16 + q * 4 + r;
                    ldso[nodeL * 132 + ch] = acc[nt][r] + bov[nt];
                }
            }
        }
    }
    __syncthreads();

    // Coalesced write-back: thread t -> node t>>3, 64B chunk t&7.
    int nl = threadIdx.x >> 3, c = threadIdx.x & 7;
    int node = node0 + nl;
    if (node < N_NODES) {
        const float* srcp = ldso + nl * 132 + c * 16;
        float* dstp = out + (size_t)node * F_DIM + c * 16;
        #pragma unroll
        for (int i = 0; i < 4; ++i)
            *(float4*)(dstp + i * 4) = *(const float4*)(srcp + i * 4);
    }
}

// ---------------------------------------------------------------------------
extern "C" void kernel_launch(void* const* d_in, const int* in_sizes, int n_in,
                              void* d_out, int out_size, void* d_ws, size_t ws_size,
                              hipStream_t stream)
{
    const float* xf  = (const float*)d_in[0];
    const float* xb  = (const float*)d_in[1];
    const int*   ei  = (const int*)d_in[2];    // [2, E] int32, row-major
    const float* Wl  = (const float*)d_in[3];
    const float* bl  = (const float*)d_in[4];
    const float* Wr  = (const float*)d_in[5];
    const float* br  = (const float*)d_in[6];
    const float* att = (const float*)d_in[7];
    const float* gb  = (const float*)d_in[8];
    const float* Wo  = (const float*)d_in[9];
    const float* bo  = (const float*)d_in[10];
    const float* dp  = (const float*)d_in[11];
    float* out = (float*)d_out;
    const int* esrc = ei;
    const int* edst = ei + N_EDGES;

    // ws layout (16B-aligned segments):
    //  xl bf16[N*64] | xr bf16[N*64] | h bf16[N*64] (bstore2 overlays h:
    //  written by bucket, read by csr, both before agg writes h) |
    //  csr_src int[ETOT] | offs int[N+4] | gtot int[208] | bofsT int[50176] |
    //  whi | wlo | wohi | wolo
    char* ws = (char*)d_ws;
    const size_t SZB = (size_t)N_NODES * H_DIM * sizeof(bf16);   // 6.4 MB
    bf16*  xl      = (bf16*)(ws);
    bf16*  xr      = (bf16*)(ws + SZB);
    bf16*  h       = (bf16*)(ws + 2 * SZB);
    unsigned* bstore2 = (unsigned*)h;         // overlay (3.2 MB <= 6.4 MB)
    int*   csr_src = (int*)(ws + 3 * SZB);
    int*   offs    = (int*)(ws + 3 * SZB + (size_t)ETOT * 4);
    int*   gtot    = offs + (N_NODES + 4);
    int*   bofsT   = gtot + 208;              // [196][256] packed (base<<16|cnt)
    bf16*  whi     = (bf16*)(bofsT + NB * 256);
    bf16*  wlo     = whi + 16384;
    bf16*  wohi    = wlo + 16384;
    bf16*  wolo    = wohi + 8192;

    prep_kernel<<<13, 256, 0, stream>>>(Wl, Wr, Wo, whi, wlo, wohi, wolo, gtot);

    bucket_kernel<<<BKT_BLKS, 256, 0, stream>>>(esrc, edst, gtot, bstore2, bofsT);

    proj_mfma<<<PROJ_BLKS, 256, 0, stream>>>(xf, xb, Wl, bl, Wr, br,
                                             whi, wlo, xl, xr);

    csr_kernel<<<NB, 512, 0, stream>>>(gtot, bstore2, bofsT, offs, csr_src);

    agg_fused<<<(N_NODES * 64) / 256, 256, 0, stream>>>(csr_src, offs,
                                                        xl, xr, att, gb, h);

    out_mfma<<<OUT_BLKS, 256, 0, stream>>>(h, wohi, wolo, bo, dp, out);
}

// Round 8
// 187.218 us; speedup vs baseline: 1.0447x; 1.0447x over previous
//
#include <hip/hip_runtime.h>
#include <hip/hip_bf16.h>
#include <math.h>

#define N_NODES 50000
#define N_EDGES 800000
#define F_DIM 128
#define H_DIM 64
#define IN_DIM 129   // F_DIM + 1 (binary feature)
#define ETOT (N_EDGES + N_NODES)          // 850000 CSR entries
#define PROJ_BLKS ((N_NODES + 31) / 32)   // 1563 (32 nodes/block)
#define NB 196                            // node buckets (256 nodes each; last has 80)
#define CAP 6144                          // csr LDS capacity (mean 4096, sigma 64)
#define EPB 3125                          // edges per bucket block (256 blocks exact)
#define BKT_BLKS 256
#define AGG_BLKS 3125                     // 16 dsts/block (50000 = 3125*16 exact)

typedef __hip_bfloat16 bf16;
typedef __attribute__((ext_vector_type(8))) short bf16x8;   // MFMA A/B frag (4 VGPR)
typedef __attribute__((ext_vector_type(4))) float f32x4;    // MFMA C/D frag

static __device__ __forceinline__ float bs2f(short s) {
    union { float f; unsigned u; } c; c.u = ((unsigned)(unsigned short)s) << 16; return c.f;
}
static __device__ __forceinline__ short f2bs(float f) {
    union { bf16 b; short s; } u; u.b = __float2bfloat16(f); return u.s;
}

// ---------------------------------------------------------------------------
// Prep: pack W (proj) and Wo (out) hi/lo MFMA B-fragments once, zero gtot.
// ---------------------------------------------------------------------------
__global__ __launch_bounds__(256) void prep_kernel(
    const float* __restrict__ Wl, const float* __restrict__ Wr,
    const float* __restrict__ Wo,
    bf16* __restrict__ whi, bf16* __restrict__ wlo,
    bf16* __restrict__ wohi, bf16* __restrict__ wolo,
    int* __restrict__ gtot)
{
    int b = blockIdx.x, t = threadIdx.x;
    if (b < 8) {                              // [Wl;Wr] frags: 2048 slots
        int s = b * 256 + t;
        int fid = s >> 6, l = s & 63;
        int wave = fid >> 3, nt = (fid >> 2) & 1, ks = fid & 3;
        int ch = wave * 32 + nt * 16 + (l & 15);
        int kb = ks * 32 + (l >> 4) * 8;
        const float* wrow = (ch < 64) ? Wl + (size_t)ch * IN_DIM
                                      : Wr + (size_t)(ch - 64) * IN_DIM;
        #pragma unroll
        for (int j = 0; j < 8; ++j) {
            float v = wrow[kb + j];
            short hs = f2bs(v);
            short ls = f2bs(v - bs2f(hs));
            ((short*)whi)[(size_t)s * 8 + j] = hs;
            ((short*)wlo)[(size_t)s * 8 + j] = ls;
        }
    } else if (b < 12) {                      // Wo frags: 1024 slots
        int s = (b - 8) * 256 + t;
        int fid = s >> 6, l = s & 63;
        int wave = fid >> 2, nt = (fid >> 1) & 1, ks = fid & 1;
        int ch = wave * 32 + nt * 16 + (l & 15);
        int kb = ks * 32 + (l >> 4) * 8;
        const float* wrow = Wo + (size_t)ch * H_DIM;
        #pragma unroll
        for (int j = 0; j < 8; ++j) {
            float v = wrow[kb + j];
            short hs = f2bs(v);
            short ls = f2bs(v - bs2f(hs));
            ((short*)wohi)[(size_t)s * 8 + j] = hs;
            ((short*)wolo)[(size_t)s * 8 + j] = ls;
        }
    } else {                                  // zero bucket totals
        if (t < NB) gtot[t] = 0;
    }
}

// ---------------------------------------------------------------------------
// H1 (hybrid dispatch — R6's best-measured config):
//  blocks [0, PROJ_BLKS):          proj: [xl|xr] = x @ [Wl;Wr]^T + bias (MFMA)
//  blocks [PROJ_BLKS, +256):       bucket sort level 1, zero returning global
//    atomics (register-staged edges, LDS histogram + scan, private scatter).
// ---------------------------------------------------------------------------
__global__ __launch_bounds__(256) void h1_kernel(
    const float* __restrict__ xf, const float* __restrict__ xb,
    const float* __restrict__ Wl, const float* __restrict__ bl,
    const float* __restrict__ Wr, const float* __restrict__ br,
    const bf16* __restrict__ whi, const bf16* __restrict__ wlo,
    const int* __restrict__ esrc, const int* __restrict__ edst,
    bf16* __restrict__ xl, bf16* __restrict__ xr,
    int* __restrict__ gtot, unsigned* __restrict__ bstore2,
    int* __restrict__ bofsT)
{
    __shared__ int smem[2048];   // 8 KB, aliased per path

    if (blockIdx.x >= PROJ_BLKS) {
        // ---- bucket path (atomic-free placement) ----
        int* hist = smem;           // 196
        int* base = smem + 256;     // 196
        int* cur  = smem + 512;     // 196
        int* shs  = smem + 768;     // 256 scan temp
        int t = threadIdx.x;
        int b = blockIdx.x - PROJ_BLKS;
        int e0 = b * EPB;
        if (t < NB) hist[t] = 0;
        __syncthreads();

        int myd[13]; int mys[13];
        #pragma unroll
        for (int i = 0; i < 13; ++i) {       // 3125 = 12*256 + 53
            int k = t + i * 256;
            bool v = k < EPB;
            int dst = v ? edst[e0 + k] : -1;
            int sc  = v ? esrc[e0 + k] : 0;
            myd[i] = dst; mys[i] = sc;
            if (v) atomicAdd(&hist[dst >> 8], 1);     // LDS atomic
        }
        __syncthreads();

        int hv = (t < NB) ? hist[t] : 0;
        shs[t] = hv;
        __syncthreads();
        #pragma unroll
        for (int d = 1; d < 256; d <<= 1) {
            int x = (t >= d) ? shs[t - d] : 0;
            __syncthreads();
            shs[t] += x;
            __syncthreads();
        }
        if (t < NB) {
            int bs = shs[t] - hv;
            base[t] = bs;
            cur[t] = 0;
            if (hv) atomicAdd(&gtot[t], hv);          // non-returning global
            bofsT[t * 256 + b] = (bs << 16) | hv;     // packed (base,count)
        }
        __syncthreads();

        #pragma unroll
        for (int i = 0; i < 13; ++i) {
            if (myd[i] >= 0) {
                int j = myd[i] >> 8;
                int slot = base[j] + atomicAdd(&cur[j], 1);   // LDS atomic
                bstore2[(size_t)e0 + slot] =
                    ((unsigned)myd[i] << 16) | (unsigned)mys[i];
            }
        }
        return;
    }

    // ---- proj path ----
    short* lds = (short*)smem;   // [node_local][ch], 16B chunks XOR-swizzled

    int wave = threadIdx.x >> 6;
    int lane = threadIdx.x & 63;
    int n = lane & 15, q = lane >> 4;
    int node0 = blockIdx.x * 32;

    bf16x8 bhi[2][4], blo_[2][4];
    float biasv[2], w128[2];
    #pragma unroll
    for (int nt = 0; nt < 2; ++nt) {
        int ch = wave * 32 + nt * 16 + n;
        #pragma unroll
        for (int ks = 0; ks < 4; ++ks) {
            int fid = wave * 8 + nt * 4 + ks;
            bhi[nt][ks]  = *(const bf16x8*)(whi + ((size_t)fid * 64 + lane) * 8);
            blo_[nt][ks] = *(const bf16x8*)(wlo + ((size_t)fid * 64 + lane) * 8);
        }
        biasv[nt] = (ch < 64) ? bl[ch] : br[ch - 64];
        w128[nt]  = (ch < 64) ? Wl[(size_t)ch * IN_DIM + 128]
                              : Wr[(size_t)(ch - 64) * IN_DIM + 128];
    }

    #pragma unroll
    for (int mt = 0; mt < 2; ++mt) {
        int nb = node0 + mt * 16;
        if (nb < N_NODES) {
            const float* xrow = xf + (size_t)(nb + n) * F_DIM;
            bf16x8 a[4];
            #pragma unroll
            for (int ks = 0; ks < 4; ++ks) {
                float4 u = *(const float4*)(xrow + ks * 32 + q * 8);
                float4 v = *(const float4*)(xrow + ks * 32 + q * 8 + 4);
                bf16x8 tt;
                tt[0] = f2bs(u.x); tt[1] = f2bs(u.y); tt[2] = f2bs(u.z); tt[3] = f2bs(u.w);
                tt[4] = f2bs(v.x); tt[5] = f2bs(v.y); tt[6] = f2bs(v.z); tt[7] = f2bs(v.w);
                a[ks] = tt;
            }
            f32x4 acc[2] = {{0.f,0.f,0.f,0.f},{0.f,0.f,0.f,0.f}};
            #pragma unroll
            for (int ks = 0; ks < 4; ++ks) {
                #pragma unroll
                for (int nt = 0; nt < 2; ++nt) {
                    acc[nt] = __builtin_amdgcn_mfma_f32_16x16x32_bf16(a[ks], bhi[nt][ks],  acc[nt], 0, 0, 0);
                    acc[nt] = __builtin_amdgcn_mfma_f32_16x16x32_bf16(a[ks], blo_[nt][ks], acc[nt], 0, 0, 0);
                }
            }
            float4 xbv = *(const float4*)(xb + nb + q * 4);
            float xbr[4] = {xbv.x, xbv.y, xbv.z, xbv.w};
            #pragma unroll
            for (int nt = 0; nt < 2; ++nt) {
                int ch = wave * 32 + nt * 16 + n;
                int blk = ch >> 3, pos = ch & 7;
                #pragma unroll
                for (int r = 0; r < 4; ++r) {
                    int nodeL = mt * 16 + q * 4 + r;   // C/D: row = quad*4 + reg
                    float val = acc[nt][r] + xbr[r] * w128[nt] + biasv[nt];
                    lds[nodeL * 128 + ((blk ^ (nodeL & 7)) << 3) + pos] = f2bs(val);
                }
            }
        }
    }
    __syncthreads();

    // Coalesced write-back: thread t -> node t>>3, 16B chunk t&7 of xl and xr.
    int nl = threadIdx.x >> 3, bk = threadIdx.x & 7;
    int node = node0 + nl;
    if (node < N_NODES) {
        bf16x8 v0 = *(const bf16x8*)(lds + nl * 128 + ((bk ^ (nl & 7)) << 3));
        *(bf16x8*)(xl + (size_t)node * H_DIM + bk * 8) = v0;
        bf16x8 v1 = *(const bf16x8*)(lds + nl * 128 + (((8 + bk) ^ (nl & 7)) << 3));
        *(bf16x8*)(xr + (size_t)node * H_DIM + bk * 8) = v1;
    }
}

// ---------------------------------------------------------------------------
// K-csr: level 2, 512 thr/block, one block per bucket (R6 verbatim).
// ---------------------------------------------------------------------------
__global__ __launch_bounds__(512) void csr_kernel(
    const int* __restrict__ gtot, const unsigned* __restrict__ bstore2,
    const int* __restrict__ bofsT,
    int* __restrict__ offs, int* __restrict__ csr_src)
{
    __shared__ unsigned ent[CAP];
    __shared__ int sh[256], gb_[256], bcnt_[256], bbase_[256];
    __shared__ int h256[256], start[256], c2[256];
    __shared__ int bb_s, C_s;
    int j = blockIdx.x, t = threadIdx.x;

    int bcnt = 0;
    if (t < 256) {
        unsigned v = (unsigned)bofsT[j * 256 + t];
        bbase_[t] = (int)(v >> 16);
        bcnt = (int)(v & 0xffffu);
        bcnt_[t] = bcnt;
        sh[t] = bcnt;
    }
    __syncthreads();
    #pragma unroll
    for (int d = 1; d < 256; d <<= 1) {
        int x = (t >= d && t < 256) ? sh[t - d] : 0;
        __syncthreads();
        if (t < 256) sh[t] += x;
        __syncthreads();
    }
    if (t < 256) gb_[t] = sh[t] - bcnt;
    if (t == 255) C_s = sh[255];
    __syncthreads();
    int C = C_s;

    if (t < 256) {
        const unsigned* p = bstore2 + (size_t)t * EPB + bbase_[t];
        int o = gb_[t];
        int c = bcnt_[t];
        for (int i = 0; i < c; ++i) ent[o + i] = p[i];
    }
    __syncthreads();

    int val = 0;
    if (t < NB) val = gtot[t] + ((t < NB - 1) ? 256 : (N_NODES - (NB - 1) * 256));
    if (t < 256) sh[t] = val;
    __syncthreads();
    #pragma unroll
    for (int d = 1; d < 256; d <<= 1) {
        int x = (t >= d && t < 256) ? sh[t - d] : 0;
        __syncthreads();
        if (t < 256) sh[t] += x;
        __syncthreads();
    }
    if (t == j) bb_s = sh[t] - val;
    if (t < 256) h256[t] = 0;
    __syncthreads();
    int bb = bb_s;

    for (int k = t; k < C; k += 512)
        atomicAdd(&h256[(ent[k] >> 16) & 255], 1);
    __syncthreads();

    int w = 0;
    if (t < 256) {
        w = h256[t] + ((j * 256 + t < N_NODES) ? 1 : 0);
        sh[t] = w;
    }
    __syncthreads();
    #pragma unroll
    for (int d = 1; d < 256; d <<= 1) {
        int x = (t >= d && t < 256) ? sh[t - d] : 0;
        __syncthreads();
        if (t < 256) sh[t] += x;
        __syncthreads();
    }
    if (t < 256) {
        int st = bb + sh[t] - w;
        start[t] = st;
        c2[t] = 0;
        int node = j * 256 + t;
        if (node < N_NODES) {
            offs[node] = st;
            csr_src[st] = node;             // self-loop at segment head
        }
    }
    if (j == NB - 1 && t == 0) offs[N_NODES] = ETOT;   // sentinel
    __syncthreads();

    for (int k = t; k < C; k += 512) {
        unsigned en = ent[k];
        int bin = (en >> 16) & 255;
        int r = atomicAdd(&c2[bin], 1);
        csr_src[start[bin] + 1 + r] = (int)(en & 0xffffu);
    }
}

// ---------------------------------------------------------------------------
// K2b+K3 fused (agg_out): 16 dsts/block (4 waves x 4 sequential dsts;
// 50000 = 3125*16 exact). Per dst: R6's depth-3 wave gather + softmax ->
// h row (bf16) into padded LDS tile [16][72]. One barrier, then the 16-node
// out-MFMA tile (B-frags from wohi/wolo pack), padded-LDS staging, coalesced
// float4 out stores. Removes the out_mfma dispatch and the 12.8 MB h
// round-trip through HBM.
// ---------------------------------------------------------------------------
__global__ __launch_bounds__(256) void agg_out(
    const int* __restrict__ csr_src, const int* __restrict__ offs,
    const bf16* __restrict__ xl, const bf16* __restrict__ xr,
    const float* __restrict__ att, const float* __restrict__ gb,
    const bf16* __restrict__ wohi, const bf16* __restrict__ wolo,
    const float* __restrict__ bo, const float* __restrict__ disp,
    float* __restrict__ out)
{
    __shared__ short hts[16 * 72];     // h tile, rows padded to 144B (4n%32 banks)
    __shared__ float ldso[16 * 132];   // out staging, +4 f32 row pad

    int wave = threadIdx.x >> 6;
    int lane = threadIdx.x & 63;
    int g  = lane >> 3;   // edge slot within batch
    int c8 = lane & 7;    // channel octet
    int node0 = blockIdx.x * 16;

    if (blockIdx.x == 0 && threadIdx.x < F_DIM) {
        float d = disp[threadIdx.x];
        out[(size_t)N_NODES * F_DIM + threadIdx.x] = (d > 20.f) ? d : log1pf(__expf(d));
    }

    // hoisted per-lane constants
    float attv[8], gbv[8];
    {
        float4 a0 = *(const float4*)(att + c8 * 8);
        float4 a1 = *(const float4*)(att + c8 * 8 + 4);
        attv[0] = a0.x; attv[1] = a0.y; attv[2] = a0.z; attv[3] = a0.w;
        attv[4] = a1.x; attv[5] = a1.y; attv[6] = a1.z; attv[7] = a1.w;
        float4 g0 = *(const float4*)(gb + c8 * 8);
        float4 g1 = *(const float4*)(gb + c8 * 8 + 4);
        gbv[0] = g0.x; gbv[1] = g0.y; gbv[2] = g0.z; gbv[3] = g0.w;
        gbv[4] = g1.x; gbv[5] = g1.y; gbv[6] = g1.z; gbv[7] = g1.w;
    }

    // ---- phase 1: 4 dsts per wave, depth-3 gather pipeline (R6 structure) ----
    #pragma unroll 1
    for (int i = 0; i < 4; ++i) {
        int wd  = wave * 4 + i;           // local dst row 0..15
        int wid = node0 + wd;             // always < N_NODES (exact grid)

        float xrv[8];
        {
            bf16x8 xrow = *(const bf16x8*)(xr + (size_t)wid * H_DIM + c8 * 8);
            #pragma unroll
            for (int j = 0; j < 8; ++j) xrv[j] = bs2f(xrow[j]);
        }

        int beg = offs[wid];
        int end = offs[wid + 1];          // >= beg+1 (self-loop)
        int last = end - 1;
        float den = 0.f;
        float acc[8] = {0.f, 0.f, 0.f, 0.f, 0.f, 0.f, 0.f, 0.f};

        int i0 = beg + g;        i0 = (i0 < end) ? i0 : last;
        int i1 = beg + 8 + g;    i1 = (i1 < end) ? i1 : last;
        int i2 = beg + 16 + g;   i2 = (i2 < end) ? i2 : last;
        int srcC = csr_src[i2];
        bf16x8 xa = *(const bf16x8*)(xl + (size_t)csr_src[i0] * H_DIM + c8 * 8);
        bf16x8 xb = *(const bf16x8*)(xl + (size_t)csr_src[i1] * H_DIM + c8 * 8);

        for (int base = beg; base < end; base += 8) {
            int i3 = base + 24 + g;  i3 = (i3 < end) ? i3 : last;
            int srcD = csr_src[i3];
            bf16x8 xc = *(const bf16x8*)(xl + (size_t)srcC * H_DIM + c8 * 8);

            bool valid = (base + g) < end;
            float xv[8], p = 0.f;
            #pragma unroll
            for (int j = 0; j < 8; ++j) {
                xv[j] = bs2f(xa[j]);
                float m = xv[j] + xrv[j];
                m = (m > 0.f) ? m : 0.2f * m;
                p += m * attv[j];
            }
            p += __shfl_xor(p, 1);
            p += __shfl_xor(p, 2);
            p += __shfl_xor(p, 4);
            float ex = valid ? __expf(p) : 0.f;
            den += ex;
            #pragma unroll
            for (int j = 0; j < 8; ++j) acc[j] += ex * xv[j];

            xa = xb;
            xb = xc;
            srcC = srcD;
        }

        #pragma unroll
        for (int j = 0; j < 8; ++j) {
            acc[j] += __shfl_xor(acc[j], 8);
            acc[j] += __shfl_xor(acc[j], 16);
            acc[j] += __shfl_xor(acc[j], 32);
        }
        den += __shfl_xor(den, 8);
        den += __shfl_xor(den, 16);
        den += __shfl_xor(den, 32);

        if (g == 0) {
            float inv = 1.0f / den;
            bf16x8 ov;
            #pragma unroll
            for (int j = 0; j < 8; ++j) {
                float v = acc[j] * inv + gbv[j];
                v = (v > 0.f) ? v : expm1f(v);
                ov[j] = f2bs(v);
            }
            *(bf16x8*)(hts + wd * 72 + c8 * 8) = ov;   // h row into LDS tile
        }
    }
    __syncthreads();

    // ---- phase 2: 16-node out-MFMA tile (out_mfma structure, single mt) ----
    int n = lane & 15, q = lane >> 4;

    bf16x8 bhi[2][2], blo_[2][2];
    float bov[2];
    #pragma unroll
    for (int nt = 0; nt < 2; ++nt) {
        int ch = wave * 32 + nt * 16 + n;
        #pragma unroll
        for (int ks = 0; ks < 2; ++ks) {
            int fid = wave * 4 + nt * 2 + ks;
            bhi[nt][ks]  = *(const bf16x8*)(wohi + ((size_t)fid * 64 + lane) * 8);
            blo_[nt][ks] = *(const bf16x8*)(wolo + ((size_t)fid * 64 + lane) * 8);
        }
        bov[nt] = bo[ch];
    }

    bf16x8 a[2];
    #pragma unroll
    for (int ks = 0; ks < 2; ++ks)
        a[ks] = *(const bf16x8*)(hts + n * 72 + ks * 32 + q * 8);
    f32x4 acc2[2] = {{0.f,0.f,0.f,0.f},{0.f,0.f,0.f,0.f}};
    #pragma unroll
    for (int ks = 0; ks < 2; ++ks) {
        #pragma unroll
        for (int nt = 0; nt < 2; ++nt) {
            acc2[nt] = __builtin_amdgcn_mfma_f32_16x16x32_bf16(a[ks], bhi[nt][ks],  acc2[nt], 0, 0, 0);
            acc2[nt] = __builtin_amdgcn_mfma_f32_16x16x32_bf16(a[ks], blo_[nt][ks], acc2[nt], 0, 0, 0);
        }
    }
    #pragma unroll
    for (int nt = 0; nt < 2; ++nt) {
        int ch = wave * 32 + nt * 16 + n;
        #pragma unroll
        for (int r = 0; r < 4; ++r) {
            int nodeL = q * 4 + r;         // C/D: row = quad*4 + reg
            ldso[nodeL * 132 + ch] = acc2[nt][r] + bov[nt];
        }
    }
    __syncthreads();

    // Coalesced write-back: thread t -> node t>>4, 32B part t&15.
    int nl = threadIdx.x >> 4, p = threadIdx.x & 15;
    const float* srcp = ldso + nl * 132 + p * 8;
    float* dstp = out + (size_t)(node0 + nl) * F_DIM + p * 8;
    *(float4*)(dstp)     = *(const float4*)(srcp);
    *(float4*)(dstp + 4) = *(const float4*)(srcp + 4);
}

// ---------------------------------------------------------------------------
extern "C" void kernel_launch(void* const* d_in, const int* in_sizes, int n_in,
                              void* d_out, int out_size, void* d_ws, size_t ws_size,
                              hipStream_t stream)
{
    const float* xf  = (const float*)d_in[0];
    const float* xb  = (const float*)d_in[1];
    const int*   ei  = (const int*)d_in[2];    // [2, E] int32, row-major
    const float* Wl  = (const float*)d_in[3];
    const float* bl  = (const float*)d_in[4];
    const float* Wr  = (const float*)d_in[5];
    const float* br  = (const float*)d_in[6];
    const float* att = (const float*)d_in[7];
    const float* gb  = (const float*)d_in[8];
    const float* Wo  = (const float*)d_in[9];
    const float* bo  = (const float*)d_in[10];
    const float* dp  = (const float*)d_in[11];
    float* out = (float*)d_out;
    const int* esrc = ei;
    const int* edst = ei + N_EDGES;

    // ws layout (16B-aligned segments):
    //  xl bf16[N*64] | xr bf16[N*64] | bstore2 u32[E] | csr_src int[ETOT] |
    //  offs int[N+4] | gtot int[208] | bofsT int[50176] | whi | wlo | wohi | wolo
    char* ws = (char*)d_ws;
    const size_t SZB = (size_t)N_NODES * H_DIM * sizeof(bf16);   // 6.4 MB
    bf16*  xl      = (bf16*)(ws);
    bf16*  xr      = (bf16*)(ws + SZB);
    unsigned* bstore2 = (unsigned*)(ws + 2 * SZB);
    int*   csr_src = (int*)(ws + 2 * SZB + (size_t)N_EDGES * 4);
    int*   offs    = csr_src + ETOT;
    int*   gtot    = offs + (N_NODES + 4);
    int*   bofsT   = gtot + 208;              // [196][256] packed (base<<16|cnt)
    bf16*  whi     = (bf16*)(bofsT + NB * 256);
    bf16*  wlo     = whi + 16384;
    bf16*  wohi    = wlo + 16384;
    bf16*  wolo    = wohi + 8192;

    prep_kernel<<<13, 256, 0, stream>>>(Wl, Wr, Wo, whi, wlo, wohi, wolo, gtot);

    h1_kernel<<<PROJ_BLKS + BKT_BLKS, 256, 0, stream>>>(
        xf, xb, Wl, bl, Wr, br, whi, wlo, esrc, edst, xl, xr,
        gtot, bstore2, bofsT);

    csr_kernel<<<NB, 512, 0, stream>>>(gtot, bstore2, bofsT, offs, csr_src);

    agg_out<<<AGG_BLKS, 256, 0, stream>>>(csr_src, offs, xl, xr, att, gb,
                                          wohi, wolo, bo, dp, out);
}

// Round 9
// 187.137 us; speedup vs baseline: 1.0452x; 1.0004x over previous
//
#include <hip/hip_runtime.h>
#include <hip/hip_bf16.h>
#include <math.h>

#define N_NODES 50000
#define N_EDGES 800000
#define F_DIM 128
#define H_DIM 64
#define IN_DIM 129   // F_DIM + 1 (binary feature)
#define ETOT (N_EDGES + N_NODES)          // 850000 CSR entries
#define PROJ_BLKS ((N_NODES + 31) / 32)   // 1563 (32 nodes/block)
#define NB 196                            // node buckets (256 nodes each; last has 80)
#define CAP 6144                          // csr LDS capacity (mean 4096, sigma 64)
#define EPB 3125                          // edges per bucket block (256 blocks exact)
#define BKT_BLKS 256
#define AGG_BLKS 3125                     // 16 dsts/block (50000 = 3125*16 exact)

typedef __hip_bfloat16 bf16;
typedef __attribute__((ext_vector_type(8))) short bf16x8;   // MFMA A/B frag (4 VGPR)
typedef __attribute__((ext_vector_type(4))) float f32x4;    // MFMA C/D frag

static __device__ __forceinline__ float bs2f(short s) {
    union { float f; unsigned u; } c; c.u = ((unsigned)(unsigned short)s) << 16; return c.f;
}
static __device__ __forceinline__ short f2bs(float f) {
    union { bf16 b; short s; } u; u.b = __float2bfloat16(f); return u.s;
}

// ---------------------------------------------------------------------------
// Prep: pack W (proj) and Wo (out) hi/lo MFMA B-fragments once, zero gtot.
// ---------------------------------------------------------------------------
__global__ __launch_bounds__(256) void prep_kernel(
    const float* __restrict__ Wl, const float* __restrict__ Wr,
    const float* __restrict__ Wo,
    bf16* __restrict__ whi, bf16* __restrict__ wlo,
    bf16* __restrict__ wohi, bf16* __restrict__ wolo,
    int* __restrict__ gtot)
{
    int b = blockIdx.x, t = threadIdx.x;
    if (b < 8) {                              // [Wl;Wr] frags: 2048 slots
        int s = b * 256 + t;
        int fid = s >> 6, l = s & 63;
        int wave = fid >> 3, nt = (fid >> 2) & 1, ks = fid & 3;
        int ch = wave * 32 + nt * 16 + (l & 15);
        int kb = ks * 32 + (l >> 4) * 8;
        const float* wrow = (ch < 64) ? Wl + (size_t)ch * IN_DIM
                                      : Wr + (size_t)(ch - 64) * IN_DIM;
        #pragma unroll
        for (int j = 0; j < 8; ++j) {
            float v = wrow[kb + j];
            short hs = f2bs(v);
            short ls = f2bs(v - bs2f(hs));
            ((short*)whi)[(size_t)s * 8 + j] = hs;
            ((short*)wlo)[(size_t)s * 8 + j] = ls;
        }
    } else if (b < 12) {                      // Wo frags: 1024 slots
        int s = (b - 8) * 256 + t;
        int fid = s >> 6, l = s & 63;
        int wave = fid >> 2, nt = (fid >> 1) & 1, ks = fid & 1;
        int ch = wave * 32 + nt * 16 + (l & 15);
        int kb = ks * 32 + (l >> 4) * 8;
        const float* wrow = Wo + (size_t)ch * H_DIM;
        #pragma unroll
        for (int j = 0; j < 8; ++j) {
            float v = wrow[kb + j];
            short hs = f2bs(v);
            short ls = f2bs(v - bs2f(hs));
            ((short*)wohi)[(size_t)s * 8 + j] = hs;
            ((short*)wolo)[(size_t)s * 8 + j] = ls;
        }
    } else {                                  // zero bucket totals
        if (t < NB) gtot[t] = 0;
    }
}

// ---------------------------------------------------------------------------
// H1 (hybrid dispatch — R6's best-measured config):
//  blocks [0, PROJ_BLKS):          proj: [xl|xr] = x @ [Wl;Wr]^T + bias (MFMA)
//  blocks [PROJ_BLKS, +256):       bucket sort level 1, zero returning global
//    atomics (register-staged edges, LDS histogram + scan, private scatter).
// ---------------------------------------------------------------------------
__global__ __launch_bounds__(256) void h1_kernel(
    const float* __restrict__ xf, const float* __restrict__ xb,
    const float* __restrict__ Wl, const float* __restrict__ bl,
    const float* __restrict__ Wr, const float* __restrict__ br,
    const bf16* __restrict__ whi, const bf16* __restrict__ wlo,
    const int* __restrict__ esrc, const int* __restrict__ edst,
    bf16* __restrict__ xl, bf16* __restrict__ xr,
    int* __restrict__ gtot, unsigned* __restrict__ bstore2,
    int* __restrict__ bofsT)
{
    __shared__ int smem[2048];   // 8 KB, aliased per path

    if (blockIdx.x >= PROJ_BLKS) {
        // ---- bucket path (atomic-free placement) ----
        int* hist = smem;           // 196
        int* base = smem + 256;     // 196
        int* cur  = smem + 512;     // 196
        int* shs  = smem + 768;     // 256 scan temp
        int t = threadIdx.x;
        int b = blockIdx.x - PROJ_BLKS;
        int e0 = b * EPB;
        if (t < NB) hist[t] = 0;
        __syncthreads();

        int myd[13]; int mys[13];
        #pragma unroll
        for (int i = 0; i < 13; ++i) {       // 3125 = 12*256 + 53
            int k = t + i * 256;
            bool v = k < EPB;
            int dst = v ? edst[e0 + k] : -1;
            int sc  = v ? esrc[e0 + k] : 0;
            myd[i] = dst; mys[i] = sc;
            if (v) atomicAdd(&hist[dst >> 8], 1);     // LDS atomic
        }
        __syncthreads();

        int hv = (t < NB) ? hist[t] : 0;
        shs[t] = hv;
        __syncthreads();
        #pragma unroll
        for (int d = 1; d < 256; d <<= 1) {
            int x = (t >= d) ? shs[t - d] : 0;
            __syncthreads();
            shs[t] += x;
            __syncthreads();
        }
        if (t < NB) {
            int bs = shs[t] - hv;
            base[t] = bs;
            cur[t] = 0;
            if (hv) atomicAdd(&gtot[t], hv);          // non-returning global
            bofsT[t * 256 + b] = (bs << 16) | hv;     // packed (base,count)
        }
        __syncthreads();

        #pragma unroll
        for (int i = 0; i < 13; ++i) {
            if (myd[i] >= 0) {
                int j = myd[i] >> 8;
                int slot = base[j] + atomicAdd(&cur[j], 1);   // LDS atomic
                bstore2[(size_t)e0 + slot] =
                    ((unsigned)myd[i] << 16) | (unsigned)mys[i];
            }
        }
        return;
    }

    // ---- proj path ----
    short* lds = (short*)smem;   // [node_local][ch], 16B chunks XOR-swizzled

    int wave = threadIdx.x >> 6;
    int lane = threadIdx.x & 63;
    int n = lane & 15, q = lane >> 4;
    int node0 = blockIdx.x * 32;

    bf16x8 bhi[2][4], blo_[2][4];
    float biasv[2], w128[2];
    #pragma unroll
    for (int nt = 0; nt < 2; ++nt) {
        int ch = wave * 32 + nt * 16 + n;
        #pragma unroll
        for (int ks = 0; ks < 4; ++ks) {
            int fid = wave * 8 + nt * 4 + ks;
            bhi[nt][ks]  = *(const bf16x8*)(whi + ((size_t)fid * 64 + lane) * 8);
            blo_[nt][ks] = *(const bf16x8*)(wlo + ((size_t)fid * 64 + lane) * 8);
        }
        biasv[nt] = (ch < 64) ? bl[ch] : br[ch - 64];
        w128[nt]  = (ch < 64) ? Wl[(size_t)ch * IN_DIM + 128]
                              : Wr[(size_t)(ch - 64) * IN_DIM + 128];
    }

    #pragma unroll
    for (int mt = 0; mt < 2; ++mt) {
        int nb = node0 + mt * 16;
        if (nb < N_NODES) {
            const float* xrow = xf + (size_t)(nb + n) * F_DIM;
            bf16x8 a[4];
            #pragma unroll
            for (int ks = 0; ks < 4; ++ks) {
                float4 u = *(const float4*)(xrow + ks * 32 + q * 8);
                float4 v = *(const float4*)(xrow + ks * 32 + q * 8 + 4);
                bf16x8 tt;
                tt[0] = f2bs(u.x); tt[1] = f2bs(u.y); tt[2] = f2bs(u.z); tt[3] = f2bs(u.w);
                tt[4] = f2bs(v.x); tt[5] = f2bs(v.y); tt[6] = f2bs(v.z); tt[7] = f2bs(v.w);
                a[ks] = tt;
            }
            f32x4 acc[2] = {{0.f,0.f,0.f,0.f},{0.f,0.f,0.f,0.f}};
            #pragma unroll
            for (int ks = 0; ks < 4; ++ks) {
                #pragma unroll
                for (int nt = 0; nt < 2; ++nt) {
                    acc[nt] = __builtin_amdgcn_mfma_f32_16x16x32_bf16(a[ks], bhi[nt][ks],  acc[nt], 0, 0, 0);
                    acc[nt] = __builtin_amdgcn_mfma_f32_16x16x32_bf16(a[ks], blo_[nt][ks], acc[nt], 0, 0, 0);
                }
            }
            float4 xbv = *(const float4*)(xb + nb + q * 4);
            float xbr[4] = {xbv.x, xbv.y, xbv.z, xbv.w};
            #pragma unroll
            for (int nt = 0; nt < 2; ++nt) {
                int ch = wave * 32 + nt * 16 + n;
                int blk = ch >> 3, pos = ch & 7;
                #pragma unroll
                for (int r = 0; r < 4; ++r) {
                    int nodeL = mt * 16 + q * 4 + r;   // C/D: row = quad*4 + reg
                    float val = acc[nt][r] + xbr[r] * w128[nt] + biasv[nt];
                    lds[nodeL * 128 + ((blk ^ (nodeL & 7)) << 3) + pos] = f2bs(val);
                }
            }
        }
    }
    __syncthreads();

    // Coalesced write-back: thread t -> node t>>3, 16B chunk t&7 of xl and xr.
    int nl = threadIdx.x >> 3, bk = threadIdx.x & 7;
    int node = node0 + nl;
    if (node < N_NODES) {
        bf16x8 v0 = *(const bf16x8*)(lds + nl * 128 + ((bk ^ (nl & 7)) << 3));
        *(bf16x8*)(xl + (size_t)node * H_DIM + bk * 8) = v0;
        bf16x8 v1 = *(const bf16x8*)(lds + nl * 128 + (((8 + bk) ^ (nl & 7)) << 3));
        *(bf16x8*)(xr + (size_t)node * H_DIM + bk * 8) = v1;
    }
}

// ---------------------------------------------------------------------------
// K-csr: level 2, 512 thr/block, one block per bucket (R6 verbatim).
// ---------------------------------------------------------------------------
__global__ __launch_bounds__(512) void csr_kernel(
    const int* __restrict__ gtot, const unsigned* __restrict__ bstore2,
    const int* __restrict__ bofsT,
    int* __restrict__ offs, int* __restrict__ csr_src)
{
    __shared__ unsigned ent[CAP];
    __shared__ int sh[256], gb_[256], bcnt_[256], bbase_[256];
    __shared__ int h256[256], start[256], c2[256];
    __shared__ int bb_s, C_s;
    int j = blockIdx.x, t = threadIdx.x;

    int bcnt = 0;
    if (t < 256) {
        unsigned v = (unsigned)bofsT[j * 256 + t];
        bbase_[t] = (int)(v >> 16);
        bcnt = (int)(v & 0xffffu);
        bcnt_[t] = bcnt;
        sh[t] = bcnt;
    }
    __syncthreads();
    #pragma unroll
    for (int d = 1; d < 256; d <<= 1) {
        int x = (t >= d && t < 256) ? sh[t - d] : 0;
        __syncthreads();
        if (t < 256) sh[t] += x;
        __syncthreads();
    }
    if (t < 256) gb_[t] = sh[t] - bcnt;
    if (t == 255) C_s = sh[255];
    __syncthreads();
    int C = C_s;

    if (t < 256) {
        const unsigned* p = bstore2 + (size_t)t * EPB + bbase_[t];
        int o = gb_[t];
        int c = bcnt_[t];
        for (int i = 0; i < c; ++i) ent[o + i] = p[i];
    }
    __syncthreads();

    int val = 0;
    if (t < NB) val = gtot[t] + ((t < NB - 1) ? 256 : (N_NODES - (NB - 1) * 256));
    if (t < 256) sh[t] = val;
    __syncthreads();
    #pragma unroll
    for (int d = 1; d < 256; d <<= 1) {
        int x = (t >= d && t < 256) ? sh[t - d] : 0;
        __syncthreads();
        if (t < 256) sh[t] += x;
        __syncthreads();
    }
    if (t == j) bb_s = sh[t] - val;
    if (t < 256) h256[t] = 0;
    __syncthreads();
    int bb = bb_s;

    for (int k = t; k < C; k += 512)
        atomicAdd(&h256[(ent[k] >> 16) & 255], 1);
    __syncthreads();

    int w = 0;
    if (t < 256) {
        w = h256[t] + ((j * 256 + t < N_NODES) ? 1 : 0);
        sh[t] = w;
    }
    __syncthreads();
    #pragma unroll
    for (int d = 1; d < 256; d <<= 1) {
        int x = (t >= d && t < 256) ? sh[t - d] : 0;
        __syncthreads();
        if (t < 256) sh[t] += x;
        __syncthreads();
    }
    if (t < 256) {
        int st = bb + sh[t] - w;
        start[t] = st;
        c2[t] = 0;
        int node = j * 256 + t;
        if (node < N_NODES) {
            offs[node] = st;
            csr_src[st] = node;             // self-loop at segment head
        }
    }
    if (j == NB - 1 && t == 0) offs[N_NODES] = ETOT;   // sentinel
    __syncthreads();

    for (int k = t; k < C; k += 512) {
        unsigned en = ent[k];
        int bin = (en >> 16) & 255;
        int r = atomicAdd(&c2[bin], 1);
        csr_src[start[bin] + 1 + r] = (int)(en & 0xffffu);
    }
}

// ---------------------------------------------------------------------------
// K2b+K3 fused (agg_out): 16 dsts/block (4 waves x 2 PAIRS of dsts).
// Each pair runs two interleaved gather streams (A/B, named registers,
// depth-3 each) -> 2x outstanding loads per wave, half the serial passes.
// The random 128B xl gathers miss the 4MB per-XCD L2 (xl = 6.4MB) -> ~L3
// latency; MLP is the lever. attv pre-scaled by log2(e) -> exp2f;
// LeakyReLU via fmaxf(m, 0.2m). Phase 2 (16-node out-MFMA tile) unchanged.
// ---------------------------------------------------------------------------
__global__ __launch_bounds__(256) void agg_out(
    const int* __restrict__ csr_src, const int* __restrict__ offs,
    const bf16* __restrict__ xl, const bf16* __restrict__ xr,
    const float* __restrict__ att, const float* __restrict__ gb,
    const bf16* __restrict__ wohi, const bf16* __restrict__ wolo,
    const float* __restrict__ bo, const float* __restrict__ disp,
    float* __restrict__ out)
{
    __shared__ short hts[16 * 72];     // h tile, rows padded to 144B
    __shared__ float ldso[16 * 132];   // out staging, +4 f32 row pad

    int wave = threadIdx.x >> 6;
    int lane = threadIdx.x & 63;
    int g  = lane >> 3;   // edge slot within batch
    int c8 = lane & 7;    // channel octet
    int node0 = blockIdx.x * 16;

    if (blockIdx.x == 0 && threadIdx.x < F_DIM) {
        float d = disp[threadIdx.x];
        out[(size_t)N_NODES * F_DIM + threadIdx.x] = (d > 20.f) ? d : log1pf(__expf(d));
    }

    // hoisted per-lane constants (attv pre-scaled by log2e for exp2f)
    float attv[8], gbv[8];
    {
        float4 a0 = *(const float4*)(att + c8 * 8);
        float4 a1 = *(const float4*)(att + c8 * 8 + 4);
        const float L2E = 1.44269504f;
        attv[0] = a0.x * L2E; attv[1] = a0.y * L2E; attv[2] = a0.z * L2E; attv[3] = a0.w * L2E;
        attv[4] = a1.x * L2E; attv[5] = a1.y * L2E; attv[6] = a1.z * L2E; attv[7] = a1.w * L2E;
        float4 g0 = *(const float4*)(gb + c8 * 8);
        float4 g1 = *(const float4*)(gb + c8 * 8 + 4);
        gbv[0] = g0.x; gbv[1] = g0.y; gbv[2] = g0.z; gbv[3] = g0.w;
        gbv[4] = g1.x; gbv[5] = g1.y; gbv[6] = g1.z; gbv[7] = g1.w;
    }

    // ---- phase 1: 2 pairs per wave; A/B streams interleaved ----
    #pragma unroll 1
    for (int pr = 0; pr < 2; ++pr) {
        int wdA = wave * 4 + pr * 2;      // local dst rows
        int wdB = wdA + 1;
        int widA = node0 + wdA;           // always < N_NODES (exact grid)
        int widB = node0 + wdB;

        float xrvA[8], xrvB[8];
        {
            bf16x8 xrA = *(const bf16x8*)(xr + (size_t)widA * H_DIM + c8 * 8);
            bf16x8 xrB = *(const bf16x8*)(xr + (size_t)widB * H_DIM + c8 * 8);
            #pragma unroll
            for (int j = 0; j < 8; ++j) {
                xrvA[j] = bs2f(xrA[j]);
                xrvB[j] = bs2f(xrB[j]);
            }
        }

        int begA = offs[widA], endA = offs[widA + 1], lastA = endA - 1;
        int begB = offs[widB], endB = offs[widB + 1], lastB = endB - 1;

        float denA = 0.f, denB = 0.f;
        float accA[8] = {0.f,0.f,0.f,0.f,0.f,0.f,0.f,0.f};
        float accB[8] = {0.f,0.f,0.f,0.f,0.f,0.f,0.f,0.f};

        int iA0 = begA + g;      iA0 = (iA0 < endA) ? iA0 : lastA;
        int iA1 = begA + 8 + g;  iA1 = (iA1 < endA) ? iA1 : lastA;
        int iA2 = begA + 16 + g; iA2 = (iA2 < endA) ? iA2 : lastA;
        int iB0 = begB + g;      iB0 = (iB0 < endB) ? iB0 : lastB;
        int iB1 = begB + 8 + g;  iB1 = (iB1 < endB) ? iB1 : lastB;
        int iB2 = begB + 16 + g; iB2 = (iB2 < endB) ? iB2 : lastB;
        int sA2 = csr_src[iA2];
        int sB2 = csr_src[iB2];
        bf16x8 rA0 = *(const bf16x8*)(xl + (size_t)csr_src[iA0] * H_DIM + c8 * 8);
        bf16x8 rB0 = *(const bf16x8*)(xl + (size_t)csr_src[iB0] * H_DIM + c8 * 8);
        bf16x8 rA1 = *(const bf16x8*)(xl + (size_t)csr_src[iA1] * H_DIM + c8 * 8);
        bf16x8 rB1 = *(const bf16x8*)(xl + (size_t)csr_src[iB1] * H_DIM + c8 * 8);

        int itA = (endA - begA + 7) >> 3;
        int itB = (endB - begB + 7) >> 3;
        int nIt = (itA > itB) ? itA : itB;
        int baseA = begA, baseB = begB;

        #pragma unroll 1
        for (int it = 0; it < nIt; ++it) {
            int iA3 = baseA + 24 + g; iA3 = (iA3 < endA) ? iA3 : lastA;
            int iB3 = baseB + 24 + g; iB3 = (iB3 < endB) ? iB3 : lastB;
            int sA3 = csr_src[iA3];
            int sB3 = csr_src[iB3];
            bf16x8 rA2 = *(const bf16x8*)(xl + (size_t)sA2 * H_DIM + c8 * 8);
            bf16x8 rB2 = *(const bf16x8*)(xl + (size_t)sB2 * H_DIM + c8 * 8);

            bool vA = (baseA + g) < endA;
            bool vB = (baseB + g) < endB;
            float xvA[8], xvB[8], pA = 0.f, pB = 0.f;
            #pragma unroll
            for (int j = 0; j < 8; ++j) {
                xvA[j] = bs2f(rA0[j]);
                xvB[j] = bs2f(rB0[j]);
                float mA = xvA[j] + xrvA[j];
                float mB = xvB[j] + xrvB[j];
                mA = fmaxf(mA, 0.2f * mA);        // LeakyReLU
                mB = fmaxf(mB, 0.2f * mB);
                pA += mA * attv[j];
                pB += mB * attv[j];
            }
            pA += __shfl_xor(pA, 1); pA += __shfl_xor(pA, 2); pA += __shfl_xor(pA, 4);
            pB += __shfl_xor(pB, 1); pB += __shfl_xor(pB, 2); pB += __shfl_xor(pB, 4);
            float exA = vA ? exp2f(pA) : 0.f;
            float exB = vB ? exp2f(pB) : 0.f;
            denA += exA;
            denB += exB;
            #pragma unroll
            for (int j = 0; j < 8; ++j) {
                accA[j] += exA * xvA[j];
                accB[j] += exB * xvB[j];
            }

            rA0 = rA1; rA1 = rA2; sA2 = sA3; baseA += 8;
            rB0 = rB1; rB1 = rB2; sB2 = sB3; baseB += 8;
        }

        #pragma unroll
        for (int j = 0; j < 8; ++j) {
            accA[j] += __shfl_xor(accA[j], 8);
            accA[j] += __shfl_xor(accA[j], 16);
            accA[j] += __shfl_xor(accA[j], 32);
            accB[j] += __shfl_xor(accB[j], 8);
            accB[j] += __shfl_xor(accB[j], 16);
            accB[j] += __shfl_xor(accB[j], 32);
        }
        denA += __shfl_xor(denA, 8); denA += __shfl_xor(denA, 16); denA += __shfl_xor(denA, 32);
        denB += __shfl_xor(denB, 8); denB += __shfl_xor(denB, 16); denB += __shfl_xor(denB, 32);

        if (g == 0) {
            float invA = 1.0f / denA;
            float invB = 1.0f / denB;
            bf16x8 ovA, ovB;
            #pragma unroll
            for (int j = 0; j < 8; ++j) {
                float va = accA[j] * invA + gbv[j];
                va = (va > 0.f) ? va : expm1f(va);
                ovA[j] = f2bs(va);
                float vb = accB[j] * invB + gbv[j];
                vb = (vb > 0.f) ? vb : expm1f(vb);
                ovB[j] = f2bs(vb);
            }
            *(bf16x8*)(hts + wdA * 72 + c8 * 8) = ovA;
            *(bf16x8*)(hts + wdB * 72 + c8 * 8) = ovB;
        }
    }
    __syncthreads();

    // ---- phase 2: 16-node out-MFMA tile (unchanged) ----
    int n = lane & 15, q = lane >> 4;

    bf16x8 bhi[2][2], blo_[2][2];
    float bov[2];
    #pragma unroll
    for (int nt = 0; nt < 2; ++nt) {
        int ch = wave * 32 + nt * 16 + n;
        #pragma unroll
        for (int ks = 0; ks < 2; ++ks) {
            int fid = wave * 4 + nt * 2 + ks;
            bhi[nt][ks]  = *(const bf16x8*)(wohi + ((size_t)fid * 64 + lane) * 8);
            blo_[nt][ks] = *(const bf16x8*)(wolo + ((size_t)fid * 64 + lane) * 8);
        }
        bov[nt] = bo[ch];
    }

    bf16x8 a[2];
    #pragma unroll
    for (int ks = 0; ks < 2; ++ks)
        a[ks] = *(const bf16x8*)(hts + n * 72 + ks * 32 + q * 8);
    f32x4 acc2[2] = {{0.f,0.f,0.f,0.f},{0.f,0.f,0.f,0.f}};
    #pragma unroll
    for (int ks = 0; ks < 2; ++ks) {
        #pragma unroll
        for (int nt = 0; nt < 2; ++nt) {
            acc2[nt] = __builtin_amdgcn_mfma_f32_16x16x32_bf16(a[ks], bhi[nt][ks],  acc2[nt], 0, 0, 0);
            acc2[nt] = __builtin_amdgcn_mfma_f32_16x16x32_bf16(a[ks], blo_[nt][ks], acc2[nt], 0, 0, 0);
        }
    }
    #pragma unroll
    for (int nt = 0; nt < 2; ++nt) {
        int ch = wave * 32 + nt * 16 + n;
        #pragma unroll
        for (int r = 0; r < 4; ++r) {
            int nodeL = q * 4 + r;         // C/D: row = quad*4 + reg
            ldso[nodeL * 132 + ch] = acc2[nt][r] + bov[nt];
        }
    }
    __syncthreads();

    // Coalesced write-back: thread t -> node t>>4, 32B part t&15.
    int nl = threadIdx.x >> 4, p = threadIdx.x & 15;
    const float* srcp = ldso + nl * 132 + p * 8;
    float* dstp = out + (size_t)(node0 + nl) * F_DIM + p * 8;
    *(float4*)(dstp)     = *(const float4*)(srcp);
    *(float4*)(dstp + 4) = *(const float4*)(srcp + 4);
}

// ---------------------------------------------------------------------------
extern "C" void kernel_launch(void* const* d_in, const int* in_sizes, int n_in,
                              void* d_out, int out_size, void* d_ws, size_t ws_size,
                              hipStream_t stream)
{
    const float* xf  = (const float*)d_in[0];
    const float* xb  = (const float*)d_in[1];
    const int*   ei  = (const int*)d_in[2];    // [2, E] int32, row-major
    const float* Wl  = (const float*)d_in[3];
    const float* bl  = (const float*)d_in[4];
    const float* Wr  = (const float*)d_in[5];
    const float* br  = (const float*)d_in[6];
    const float* att = (const float*)d_in[7];
    const float* gb  = (const float*)d_in[8];
    const float* Wo  = (const float*)d_in[9];
    const float* bo  = (const float*)d_in[10];
    const float* dp  = (const float*)d_in[11];
    float* out = (float*)d_out;
    const int* esrc = ei;
    const int* edst = ei + N_EDGES;

    // ws layout (16B-aligned segments):
    //  xl bf16[N*64] | xr bf16[N*64] | bstore2 u32[E] | csr_src int[ETOT] |
    //  offs int[N+4] | gtot int[208] | bofsT int[50176] | whi | wlo | wohi | wolo
    char* ws = (char*)d_ws;
    const size_t SZB = (size_t)N_NODES * H_DIM * sizeof(bf16);   // 6.4 MB
    bf16*  xl      = (bf16*)(ws);
    bf16*  xr      = (bf16*)(ws + SZB);
    unsigned* bstore2 = (unsigned*)(ws + 2 * SZB);
    int*   csr_src = (int*)(ws + 2 * SZB + (size_t)N_EDGES * 4);
    int*   offs    = csr_src + ETOT;
    int*   gtot    = offs + (N_NODES + 4);
    int*   bofsT   = gtot + 208;              // [196][256] packed (base<<16|cnt)
    bf16*  whi     = (bf16*)(bofsT + NB * 256);
    bf16*  wlo     = whi + 16384;
    bf16*  wohi    = wlo + 16384;
    bf16*  wolo    = wohi + 8192;

    prep_kernel<<<13, 256, 0, stream>>>(Wl, Wr, Wo, whi, wlo, wohi, wolo, gtot);

    h1_kernel<<<PROJ_BLKS + BKT_BLKS, 256, 0, stream>>>(
        xf, xb, Wl, bl, Wr, br, whi, wlo, esrc, edst, xl, xr,
        gtot, bstore2, bofsT);

    csr_kernel<<<NB, 512, 0, stream>>>(gtot, bstore2, bofsT, offs, csr_src);

    agg_out<<<AGG_BLKS, 256, 0, stream>>>(csr_src, offs, xl, xr, att, gb,
                                          wohi, wolo, bo, dp, out);
}

// Round 11
// 184.196 us; speedup vs baseline: 1.0619x; 1.0160x over previous
//
#include <hip/hip_runtime.h>
#include <hip/hip_bf16.h>
#include <math.h>

#define N_NODES 50000
#define N_EDGES 800000
#define F_DIM 128
#define H_DIM 64
#define IN_DIM 129   // F_DIM + 1 (binary feature)
#define ETOT (N_EDGES + N_NODES)          // 850000 CSR entries
#define NB 196                            // node buckets (256 nodes each; last has 80)
#define CAP 6144                          // csr LDS capacity (mean 4096, sigma 64)
#define EPB 3125                          // edges per bucket block (256 blocks exact)
#define BKT_BLKS 256
#define PROJ_A 782                        // proj blocks in K2 (nodes 0..25023)
#define PROJ_B 781                        // proj blocks in K3 (nodes 25024..49999)
#define AGG_BLKS 3125                     // 16 dsts/block (50000 = 3125*16 exact)

typedef __hip_bfloat16 bf16;
typedef __attribute__((ext_vector_type(8))) short bf16x8;   // MFMA A/B frag (4 VGPR)
typedef __attribute__((ext_vector_type(4))) float f32x4;    // MFMA C/D frag

static __device__ __forceinline__ float bs2f(short s) {
    union { float f; unsigned u; } c; c.u = ((unsigned)(unsigned short)s) << 16; return c.f;
}
static __device__ __forceinline__ short f2bs(float f) {
    union { bf16 b; short s; } u; u.b = __float2bfloat16(f); return u.s;
}

// ---------------------------------------------------------------------------
// Proj body (shared by K2/K3): 32 nodes starting at node0, [xl|xr] =
// x @ [Wl;Wr]^T + bias via MFMA; epilogue through XOR-swizzled LDS tile
// (8 KB region passed in) -> coalesced bf16x8 stores.
// ---------------------------------------------------------------------------
static __device__ __forceinline__ void proj_body(
    int node0, short* lds,
    const float* __restrict__ xf, const float* __restrict__ xb,
    const float* __restrict__ Wl, const float* __restrict__ bl,
    const float* __restrict__ Wr, const float* __restrict__ br,
    const bf16* __restrict__ whi, const bf16* __restrict__ wlo,
    bf16* __restrict__ xl, bf16* __restrict__ xr)
{
    int wave = threadIdx.x >> 6;
    int lane = threadIdx.x & 63;
    int n = lane & 15, q = lane >> 4;

    bf16x8 bhi[2][4], blo_[2][4];
    float biasv[2], w128[2];
    #pragma unroll
    for (int nt = 0; nt < 2; ++nt) {
        int ch = wave * 32 + nt * 16 + n;
        #pragma unroll
        for (int ks = 0; ks < 4; ++ks) {
            int fid = wave * 8 + nt * 4 + ks;
            bhi[nt][ks]  = *(const bf16x8*)(whi + ((size_t)fid * 64 + lane) * 8);
            blo_[nt][ks] = *(const bf16x8*)(wlo + ((size_t)fid * 64 + lane) * 8);
        }
        biasv[nt] = (ch < 64) ? bl[ch] : br[ch - 64];
        w128[nt]  = (ch < 64) ? Wl[(size_t)ch * IN_DIM + 128]
                              : Wr[(size_t)(ch - 64) * IN_DIM + 128];
    }

    #pragma unroll
    for (int mt = 0; mt < 2; ++mt) {
        int nb = node0 + mt * 16;
        if (nb < N_NODES) {
            const float* xrow = xf + (size_t)(nb + n) * F_DIM;
            bf16x8 a[4];
            #pragma unroll
            for (int ks = 0; ks < 4; ++ks) {
                float4 u = *(const float4*)(xrow + ks * 32 + q * 8);
                float4 v = *(const float4*)(xrow + ks * 32 + q * 8 + 4);
                bf16x8 tt;
                tt[0] = f2bs(u.x); tt[1] = f2bs(u.y); tt[2] = f2bs(u.z); tt[3] = f2bs(u.w);
                tt[4] = f2bs(v.x); tt[5] = f2bs(v.y); tt[6] = f2bs(v.z); tt[7] = f2bs(v.w);
                a[ks] = tt;
            }
            f32x4 acc[2] = {{0.f,0.f,0.f,0.f},{0.f,0.f,0.f,0.f}};
            #pragma unroll
            for (int ks = 0; ks < 4; ++ks) {
                #pragma unroll
                for (int nt = 0; nt < 2; ++nt) {
                    acc[nt] = __builtin_amdgcn_mfma_f32_16x16x32_bf16(a[ks], bhi[nt][ks],  acc[nt], 0, 0, 0);
                    acc[nt] = __builtin_amdgcn_mfma_f32_16x16x32_bf16(a[ks], blo_[nt][ks], acc[nt], 0, 0, 0);
                }
            }
            float4 xbv = *(const float4*)(xb + nb + q * 4);
            float xbr[4] = {xbv.x, xbv.y, xbv.z, xbv.w};
            #pragma unroll
            for (int nt = 0; nt < 2; ++nt) {
                int ch = wave * 32 + nt * 16 + n;
                int blk = ch >> 3, pos = ch & 7;
                #pragma unroll
                for (int r = 0; r < 4; ++r) {
                    int nodeL = mt * 16 + q * 4 + r;   // C/D: row = quad*4 + reg
                    float val = acc[nt][r] + xbr[r] * w128[nt] + biasv[nt];
                    lds[nodeL * 128 + ((blk ^ (nodeL & 7)) << 3) + pos] = f2bs(val);
                }
            }
        }
    }
    __syncthreads();

    // Coalesced write-back: thread t -> node t>>3, 16B chunk t&7 of xl and xr.
    int nl = threadIdx.x >> 3, bk = threadIdx.x & 7;
    int node = node0 + nl;
    if (node < N_NODES) {
        bf16x8 v0 = *(const bf16x8*)(lds + nl * 128 + ((bk ^ (nl & 7)) << 3));
        *(bf16x8*)(xl + (size_t)node * H_DIM + bk * 8) = v0;
        bf16x8 v1 = *(const bf16x8*)(lds + nl * 128 + (((8 + bk) ^ (nl & 7)) << 3));
        *(bf16x8*)(xr + (size_t)node * H_DIM + bk * 8) = v1;
    }
}

// ---------------------------------------------------------------------------
// Prep: pack W (proj) and Wo (out) hi/lo MFMA B-fragments once, zero gtot.
// ---------------------------------------------------------------------------
__global__ __launch_bounds__(256) void prep_kernel(
    const float* __restrict__ Wl, const float* __restrict__ Wr,
    const float* __restrict__ Wo,
    bf16* __restrict__ whi, bf16* __restrict__ wlo,
    bf16* __restrict__ wohi, bf16* __restrict__ wolo,
    int* __restrict__ gtot)
{
    int b = blockIdx.x, t = threadIdx.x;
    if (b < 8) {                              // [Wl;Wr] frags: 2048 slots
        int s = b * 256 + t;
        int fid = s >> 6, l = s & 63;
        int wave = fid >> 3, nt = (fid >> 2) & 1, ks = fid & 3;
        int ch = wave * 32 + nt * 16 + (l & 15);
        int kb = ks * 32 + (l >> 4) * 8;
        const float* wrow = (ch < 64) ? Wl + (size_t)ch * IN_DIM
                                      : Wr + (size_t)(ch - 64) * IN_DIM;
        #pragma unroll
        for (int j = 0; j < 8; ++j) {
            float v = wrow[kb + j];
            short hs = f2bs(v);
            short ls = f2bs(v - bs2f(hs));
            ((short*)whi)[(size_t)s * 8 + j] = hs;
            ((short*)wlo)[(size_t)s * 8 + j] = ls;
        }
    } else if (b < 12) {                      // Wo frags: 1024 slots
        int s = (b - 8) * 256 + t;
        int fid = s >> 6, l = s & 63;
        int wave = fid >> 2, nt = (fid >> 1) & 1, ks = fid & 1;
        int ch = wave * 32 + nt * 16 + (l & 15);
        int kb = ks * 32 + (l >> 4) * 8;
        const float* wrow = Wo + (size_t)ch * H_DIM;
        #pragma unroll
        for (int j = 0; j < 8; ++j) {
            float v = wrow[kb + j];
            short hs = f2bs(v);
            short ls = f2bs(v - bs2f(hs));
            ((short*)wohi)[(size_t)s * 8 + j] = hs;
            ((short*)wolo)[(size_t)s * 8 + j] = ls;
        }
    } else {                                  // zero bucket totals
        if (t < NB) gtot[t] = 0;
    }
}

// ---------------------------------------------------------------------------
// K2 (hybrid): blocks [0,256) bucket sort level 1 (atomic-free placement);
// blocks [256, +PROJ_A) proj nodes [0, 25024). Bucket blocks first so their
// latency hides under proj occupancy.
// ---------------------------------------------------------------------------
__global__ __launch_bounds__(256) void h2_kernel(
    const float* __restrict__ xf, const float* __restrict__ xb,
    const float* __restrict__ Wl, const float* __restrict__ bl,
    const float* __restrict__ Wr, const float* __restrict__ br,
    const bf16* __restrict__ whi, const bf16* __restrict__ wlo,
    const int* __restrict__ esrc, const int* __restrict__ edst,
    bf16* __restrict__ xl, bf16* __restrict__ xr,
    int* __restrict__ gtot, unsigned* __restrict__ bstore2,
    int* __restrict__ bofsT)
{
    __shared__ int smem[2048];   // 8 KB, aliased per path

    if (blockIdx.x < BKT_BLKS) {
        // ---- bucket path (atomic-free placement) ----
        int* hist = smem;           // 196
        int* base = smem + 256;     // 196
        int* cur  = smem + 512;     // 196
        int* shs  = smem + 768;     // 256 scan temp
        int t = threadIdx.x;
        int b = blockIdx.x;
        int e0 = b * EPB;
        if (t < NB) hist[t] = 0;
        __syncthreads();

        int myd[13]; int mys[13];
        #pragma unroll
        for (int i = 0; i < 13; ++i) {       // 3125 = 12*256 + 53
            int k = t + i * 256;
            bool v = k < EPB;
            int dst = v ? edst[e0 + k] : -1;
            int sc  = v ? esrc[e0 + k] : 0;
            myd[i] = dst; mys[i] = sc;
            if (v) atomicAdd(&hist[dst >> 8], 1);     // LDS atomic
        }
        __syncthreads();

        int hv = (t < NB) ? hist[t] : 0;
        shs[t] = hv;
        __syncthreads();
        #pragma unroll
        for (int d = 1; d < 256; d <<= 1) {
            int x = (t >= d) ? shs[t - d] : 0;
            __syncthreads();
            shs[t] += x;
            __syncthreads();
        }
        if (t < NB) {
            int bs = shs[t] - hv;
            base[t] = bs;
            cur[t] = 0;
            if (hv) atomicAdd(&gtot[t], hv);          // non-returning global
            bofsT[t * 256 + b] = (bs << 16) | hv;     // packed (base,count)
        }
        __syncthreads();

        #pragma unroll
        for (int i = 0; i < 13; ++i) {
            if (myd[i] >= 0) {
                int j = myd[i] >> 8;
                int slot = base[j] + atomicAdd(&cur[j], 1);   // LDS atomic
                bstore2[(size_t)e0 + slot] =
                    ((unsigned)myd[i] << 16) | (unsigned)mys[i];
            }
        }
        return;
    }

    proj_body((blockIdx.x - BKT_BLKS) * 32, (short*)smem,
              xf, xb, Wl, bl, Wr, br, whi, wlo, xl, xr);
}

// ---------------------------------------------------------------------------
// K3 (hybrid): blocks [0,196) csr level 2 (one bucket each, 256 thr);
// blocks [196, +PROJ_B) proj nodes [25024, 50000). csr's serial gather/scan
// latency hides under the ~780 proj blocks resident on the same CUs.
// ---------------------------------------------------------------------------
__global__ __launch_bounds__(256) void h3_kernel(
    const float* __restrict__ xf, const float* __restrict__ xb,
    const float* __restrict__ Wl, const float* __restrict__ bl,
    const float* __restrict__ Wr, const float* __restrict__ br,
    const bf16* __restrict__ whi, const bf16* __restrict__ wlo,
    bf16* __restrict__ xl, bf16* __restrict__ xr,
    const int* __restrict__ gtot, const unsigned* __restrict__ bstore2,
    const int* __restrict__ bofsT,
    int* __restrict__ offs, int* __restrict__ csr_src)
{
    __shared__ int smem3[7176];   // 28.7 KB: ent[CAP] | sh | h256 | start | c2 | scal

    if (blockIdx.x < NB) {
        // ---- csr path ----
        unsigned* ent = (unsigned*)smem3;          // CAP
        int* sh    = smem3 + CAP;                  // 256
        int* h256  = smem3 + CAP + 256;            // 256
        int* start = smem3 + CAP + 512;            // 256
        int* c2    = smem3 + CAP + 768;            // 256
        int* scal  = smem3 + CAP + 1024;           // [0]=C, [1]=bb
        int j = blockIdx.x, t = threadIdx.x;

        unsigned v = (unsigned)bofsT[j * 256 + t];
        int bbase = (int)(v >> 16);
        int bcnt  = (int)(v & 0xffffu);
        sh[t] = bcnt;
        __syncthreads();
        #pragma unroll
        for (int d = 1; d < 256; d <<= 1) {
            int x = (t >= d) ? sh[t - d] : 0;
            __syncthreads();
            sh[t] += x;
            __syncthreads();
        }
        int gb = sh[t] - bcnt;
        if (t == 255) scal[0] = sh[255];
        __syncthreads();
        int C = scal[0];

        // gather this bucket's entries into LDS (per-thread source slice)
        {
            const unsigned* p = bstore2 + (size_t)t * EPB + bbase;
            for (int i = 0; i < bcnt; ++i) ent[gb + i] = p[i];
        }
        __syncthreads();

        // bucket-base prefix: val_j' = gtot[j'] + (real nodes in bucket j')
        int val = 0;
        if (t < NB) val = gtot[t] + ((t < NB - 1) ? 256 : (N_NODES - (NB - 1) * 256));
        sh[t] = val;
        __syncthreads();
        #pragma unroll
        for (int d = 1; d < 256; d <<= 1) {
            int x = (t >= d) ? sh[t - d] : 0;
            __syncthreads();
            sh[t] += x;
            __syncthreads();
        }
        if (t == j) scal[1] = sh[t] - val;     // exclusive prefix at own bucket
        h256[t] = 0;
        __syncthreads();
        int bb = scal[1];

        // 256-bin histogram over entries
        for (int k = t; k < C; k += 256)
            atomicAdd(&h256[(ent[k] >> 16) & 255], 1);   // LDS atomic
        __syncthreads();

        // scan of per-node widths (deg + 1 self-loop for real nodes)
        int node = j * 256 + t;
        int w = h256[t] + ((node < N_NODES) ? 1 : 0);
        sh[t] = w;
        __syncthreads();
        #pragma unroll
        for (int d = 1; d < 256; d <<= 1) {
            int x = (t >= d) ? sh[t - d] : 0;
            __syncthreads();
            sh[t] += x;
            __syncthreads();
        }
        int st = bb + sh[t] - w;
        start[t] = st;
        c2[t] = 0;
        if (node < N_NODES) {
            offs[node] = st;
            csr_src[st] = node;                 // self-loop at segment head
        }
        if (j == NB - 1 && t == 0) offs[N_NODES] = ETOT;   // sentinel
        __syncthreads();

        for (int k = t; k < C; k += 256) {
            unsigned en = ent[k];
            int bin = (en >> 16) & 255;
            int r = atomicAdd(&c2[bin], 1);     // LDS atomic
            csr_src[start[bin] + 1 + r] = (int)(en & 0xffffu);
        }
        return;
    }

    proj_body((PROJ_A + blockIdx.x - NB) * 32, (short*)smem3,
              xf, xb, Wl, bl, Wr, br, whi, wlo, xl, xr);
}

// ---------------------------------------------------------------------------
// K2b+K3 fused (agg_out): R9 verbatim — 16 dsts/block, 4 waves x 2 pairs,
// A/B interleaved depth-3 gather streams, exp2f, fmaxf LeakyReLU; phase 2:
// 16-node out-MFMA tile.
// ---------------------------------------------------------------------------
__global__ __launch_bounds__(256) void agg_out(
    const int* __restrict__ csr_src, const int* __restrict__ offs,
    const bf16* __restrict__ xl, const bf16* __restrict__ xr,
    const float* __restrict__ att, const float* __restrict__ gb,
    const bf16* __restrict__ wohi, const bf16* __restrict__ wolo,
    const float* __restrict__ bo, const float* __restrict__ disp,
    float* __restrict__ out)
{
    __shared__ short hts[16 * 72];     // h tile, rows padded to 144B
    __shared__ float ldso[16 * 132];   // out staging, +4 f32 row pad

    int wave = threadIdx.x >> 6;
    int lane = threadIdx.x & 63;
    int g  = lane >> 3;   // edge slot within batch
    int c8 = lane & 7;    // channel octet
    int node0 = blockIdx.x * 16;

    if (blockIdx.x == 0 && threadIdx.x < F_DIM) {
        float d = disp[threadIdx.x];
        out[(size_t)N_NODES * F_DIM + threadIdx.x] = (d > 20.f) ? d : log1pf(__expf(d));
    }

    float attv[8], gbv[8];
    {
        float4 a0 = *(const float4*)(att + c8 * 8);
        float4 a1 = *(const float4*)(att + c8 * 8 + 4);
        const float L2E = 1.44269504f;
        attv[0] = a0.x * L2E; attv[1] = a0.y * L2E; attv[2] = a0.z * L2E; attv[3] = a0.w * L2E;
        attv[4] = a1.x * L2E; attv[5] = a1.y * L2E; attv[6] = a1.z * L2E; attv[7] = a1.w * L2E;
        float4 g0 = *(const float4*)(gb + c8 * 8);
        float4 g1 = *(const float4*)(gb + c8 * 8 + 4);
        gbv[0] = g0.x; gbv[1] = g0.y; gbv[2] = g0.z; gbv[3] = g0.w;
        gbv[4] = g1.x; gbv[5] = g1.y; gbv[6] = g1.z; gbv[7] = g1.w;
    }

    #pragma unroll 1
    for (int pr = 0; pr < 2; ++pr) {
        int wdA = wave * 4 + pr * 2;
        int wdB = wdA + 1;
        int widA = node0 + wdA;
        int widB = node0 + wdB;

        float xrvA[8], xrvB[8];
        {
            bf16x8 xrA = *(const bf16x8*)(xr + (size_t)widA * H_DIM + c8 * 8);
            bf16x8 xrB = *(const bf16x8*)(xr + (size_t)widB * H_DIM + c8 * 8);
            #pragma unroll
            for (int j = 0; j < 8; ++j) {
                xrvA[j] = bs2f(xrA[j]);
                xrvB[j] = bs2f(xrB[j]);
            }
        }

        int begA = offs[widA], endA = offs[widA + 1], lastA = endA - 1;
        int begB = offs[widB], endB = offs[widB + 1], lastB = endB - 1;

        float denA = 0.f, denB = 0.f;
        float accA[8] = {0.f,0.f,0.f,0.f,0.f,0.f,0.f,0.f};
        float accB[8] = {0.f,0.f,0.f,0.f,0.f,0.f,0.f,0.f};

        int iA0 = begA + g;      iA0 = (iA0 < endA) ? iA0 : lastA;
        int iA1 = begA + 8 + g;  iA1 = (iA1 < endA) ? iA1 : lastA;
        int iA2 = begA + 16 + g; iA2 = (iA2 < endA) ? iA2 : lastA;
        int iB0 = begB + g;      iB0 = (iB0 < endB) ? iB0 : lastB;
        int iB1 = begB + 8 + g;  iB1 = (iB1 < endB) ? iB1 : lastB;
        int iB2 = begB + 16 + g; iB2 = (iB2 < endB) ? iB2 : lastB;
        int sA2 = csr_src[iA2];
        int sB2 = csr_src[iB2];
        bf16x8 rA0 = *(const bf16x8*)(xl + (size_t)csr_src[iA0] * H_DIM + c8 * 8);
        bf16x8 rB0 = *(const bf16x8*)(xl + (size_t)csr_src[iB0] * H_DIM + c8 * 8);
        bf16x8 rA1 = *(const bf16x8*)(xl + (size_t)csr_src[iA1] * H_DIM + c8 * 8);
        bf16x8 rB1 = *(const bf16x8*)(xl + (size_t)csr_src[iB1] * H_DIM + c8 * 8);

        int itA = (endA - begA + 7) >> 3;
        int itB = (endB - begB + 7) >> 3;
        int nIt = (itA > itB) ? itA : itB;
        int baseA = begA, baseB = begB;

        #pragma unroll 1
        for (int it = 0; it < nIt; ++it) {
            int iA3 = baseA + 24 + g; iA3 = (iA3 < endA) ? iA3 : lastA;
            int iB3 = baseB + 24 + g; iB3 = (iB3 < endB) ? iB3 : lastB;
            int sA3 = csr_src[iA3];
            int sB3 = csr_src[iB3];
            bf16x8 rA2 = *(const bf16x8*)(xl + (size_t)sA2 * H_DIM + c8 * 8);
            bf16x8 rB2 = *(const bf16x8*)(xl + (size_t)sB2 * H_DIM + c8 * 8);

            bool vA = (baseA + g) < endA;
            bool vB = (baseB + g) < endB;
            float xvA[8], xvB[8], pA = 0.f, pB = 0.f;
            #pragma unroll
            for (int j = 0; j < 8; ++j) {
                xvA[j] = bs2f(rA0[j]);
                xvB[j] = bs2f(rB0[j]);
                float mA = xvA[j] + xrvA[j];
                float mB = xvB[j] + xrvB[j];
                mA = fmaxf(mA, 0.2f * mA);        // LeakyReLU
                mB = fmaxf(mB, 0.2f * mB);
                pA += mA * attv[j];
                pB += mB * attv[j];
            }
            pA += __shfl_xor(pA, 1); pA += __shfl_xor(pA, 2); pA += __shfl_xor(pA, 4);
            pB += __shfl_xor(pB, 1); pB += __shfl_xor(pB, 2); pB += __shfl_xor(pB, 4);
            float exA = vA ? exp2f(pA) : 0.f;
            float exB = vB ? exp2f(pB) : 0.f;
            denA += exA;
            denB += exB;
            #pragma unroll
            for (int j = 0; j < 8; ++j) {
                accA[j] += exA * xvA[j];
                accB[j] += exB * xvB[j];
            }

            rA0 = rA1; rA1 = rA2; sA2 = sA3; baseA += 8;
            rB0 = rB1; rB1 = rB2; sB2 = sB3; baseB += 8;
        }

        #pragma unroll
        for (int j = 0; j < 8; ++j) {
            accA[j] += __shfl_xor(accA[j], 8);
            accA[j] += __shfl_xor(accA[j], 16);
            accA[j] += __shfl_xor(accA[j], 32);
            accB[j] += __shfl_xor(accB[j], 8);
            accB[j] += __shfl_xor(accB[j], 16);
            accB[j] += __shfl_xor(accB[j], 32);
        }
        denA += __shfl_xor(denA, 8); denA += __shfl_xor(denA, 16); denA += __shfl_xor(denA, 32);
        denB += __shfl_xor(denB, 8); denB += __shfl_xor(denB, 16); denB += __shfl_xor(denB, 32);

        if (g == 0) {
            float invA = 1.0f / denA;
            float invB = 1.0f / denB;
            bf16x8 ovA, ovB;
            #pragma unroll
            for (int j = 0; j < 8; ++j) {
                float va = accA[j] * invA + gbv[j];
                va = (va > 0.f) ? va : expm1f(va);
                ovA[j] = f2bs(va);
                float vb = accB[j] * invB + gbv[j];
                vb = (vb > 0.f) ? vb : expm1f(vb);
                ovB[j] = f2bs(vb);
            }
            *(bf16x8*)(hts + wdA * 72 + c8 * 8) = ovA;
            *(bf16x8*)(hts + wdB * 72 + c8 * 8) = ovB;
        }
    }
    __syncthreads();

    // ---- phase 2: 16-node out-MFMA tile ----
    int n = lane & 15, q = lane >> 4;

    bf16x8 bhi[2][2], blo_[2][2];
    float bov[2];
    #pragma unroll
    for (int nt = 0; nt < 2; ++nt) {
        int ch = wave * 32 + nt * 16 + n;
        #pragma unroll
        for (int ks = 0; ks < 2; ++ks) {
            int fid = wave * 4 + nt * 2 + ks;
            bhi[nt][ks]  = *(const bf16x8*)(wohi + ((size_t)fid * 64 + lane) * 8);
            blo_[nt][ks] = *(const bf16x8*)(wolo + ((size_t)fid * 64 + lane) * 8);
        }
        bov[nt] = bo[ch];
    }

    bf16x8 a[2];
    #pragma unroll
    for (int ks = 0; ks < 2; ++ks)
        a[ks] = *(const bf16x8*)(hts + n * 72 + ks * 32 + q * 8);
    f32x4 acc2[2] = {{0.f,0.f,0.f,0.f},{0.f,0.f,0.f,0.f}};
    #pragma unroll
    for (int ks = 0; ks < 2; ++ks) {
        #pragma unroll
        for (int nt = 0; nt < 2; ++nt) {
            acc2[nt] = __builtin_amdgcn_mfma_f32_16x16x32_bf16(a[ks], bhi[nt][ks],  acc2[nt], 0, 0, 0);
            acc2[nt] = __builtin_amdgcn_mfma_f32_16x16x32_bf16(a[ks], blo_[nt][ks], acc2[nt], 0, 0, 0);
        }
    }
    #pragma unroll
    for (int nt = 0; nt < 2; ++nt) {
        int ch = wave * 32 + nt * 16 + n;
        #pragma unroll
        for (int r = 0; r < 4; ++r) {
            int nodeL = q * 4 + r;         // C/D: row = quad*4 + reg
            ldso[nodeL * 132 + ch] = acc2[nt][r] + bov[nt];
        }
    }
    __syncthreads();

    // Coalesced write-back: thread t -> node t>>4, 32B part t&15.
    int nl = threadIdx.x >> 4, p = threadIdx.x & 15;
    const float* srcp = ldso + nl * 132 + p * 8;
    float* dstp = out + (size_t)(node0 + nl) * F_DIM + p * 8;
    *(float4*)(dstp)     = *(const float4*)(srcp);
    *(float4*)(dstp + 4) = *(const float4*)(srcp + 4);
}

// ---------------------------------------------------------------------------
extern "C" void kernel_launch(void* const* d_in, const int* in_sizes, int n_in,
                              void* d_out, int out_size, void* d_ws, size_t ws_size,
                              hipStream_t stream)
{
    const float* xf  = (const float*)d_in[0];
    const float* xb  = (const float*)d_in[1];
    const int*   ei  = (const int*)d_in[2];    // [2, E] int32, row-major
    const float* Wl  = (const float*)d_in[3];
    const float* bl  = (const float*)d_in[4];
    const float* Wr  = (const float*)d_in[5];
    const float* br  = (const float*)d_in[6];
    const float* att = (const float*)d_in[7];
    const float* gb  = (const float*)d_in[8];
    const float* Wo  = (const float*)d_in[9];
    const float* bo  = (const float*)d_in[10];
    const float* dp  = (const float*)d_in[11];
    float* out = (float*)d_out;
    const int* esrc = ei;
    const int* edst = ei + N_EDGES;

    // ws layout (16B-aligned segments):
    //  xl bf16[N*64] | xr bf16[N*64] | bstore2 u32[E] | csr_src int[ETOT] |
    //  offs int[N+4] | gtot int[208] | bofsT int[50176] | whi | wlo | wohi | wolo
    char* ws = (char*)d_ws;
    const size_t SZB = (size_t)N_NODES * H_DIM * sizeof(bf16);   // 6.4 MB
    bf16*  xl      = (bf16*)(ws);
    bf16*  xr      = (bf16*)(ws + SZB);
    unsigned* bstore2 = (unsigned*)(ws + 2 * SZB);
    int*   csr_src = (int*)(ws + 2 * SZB + (size_t)N_EDGES * 4);
    int*   offs    = csr_src + ETOT;
    int*   gtot    = offs + (N_NODES + 4);
    int*   bofsT   = gtot + 208;              // [196][256] packed (base<<16|cnt)
    bf16*  whi     = (bf16*)(bofsT + NB * 256);
    bf16*  wlo     = whi + 16384;
    bf16*  wohi    = wlo + 16384;
    bf16*  wolo    = wohi + 8192;

    prep_kernel<<<13, 256, 0, stream>>>(Wl, Wr, Wo, whi, wlo, wohi, wolo, gtot);

    h2_kernel<<<BKT_BLKS + PROJ_A, 256, 0, stream>>>(
        xf, xb, Wl, bl, Wr, br, whi, wlo, esrc, edst, xl, xr,
        gtot, bstore2, bofsT);

    h3_kernel<<<NB + PROJ_B, 256, 0, stream>>>(
        xf, xb, Wl, bl, Wr, br, whi, wlo, xl, xr,
        gtot, bstore2, bofsT, offs, csr_src);

    agg_out<<<AGG_BLKS, 256, 0, stream>>>(csr_src, offs, xl, xr, att, gb,
                                          wohi, wolo, bo, dp, out);
}

// Round 14
// 165.699 us; speedup vs baseline: 1.1804x; 1.1116x over previous
//
#include <hip/hip_runtime.h>
#include <hip/hip_bf16.h>
#include <math.h>

#define N_NODES 50000
#define N_EDGES 800000
#define F_DIM 128
#define H_DIM 64
#define IN_DIM 129   // F_DIM + 1 (binary feature)
#define ETOT (N_EDGES + N_NODES)          // 850000 CSR entries
#define NB 196                            // node buckets (256 nodes each; last has 80)
#define CAP 6144                          // csr LDS capacity (mean 4096, sigma 64)
#define EPB 3125                          // edges per bucket block (256 blocks exact)
#define BKT_BLKS 256
#define PROJ_A 782                        // proj blocks in K2 (nodes 0..25023)
#define PROJ_B 781                        // proj blocks in K3 (nodes 25024..49999)
#define AGG_BLKS 3125                     // 16 dsts/block (50000 = 3125*16 exact)

typedef __hip_bfloat16 bf16;
typedef __attribute__((ext_vector_type(8))) short bf16x8;   // MFMA A/B frag (4 VGPR)
typedef __attribute__((ext_vector_type(4))) float f32x4;    // MFMA C/D frag

static __device__ __forceinline__ float bs2f(short s) {
    union { float f; unsigned u; } c; c.u = ((unsigned)(unsigned short)s) << 16; return c.f;
}
static __device__ __forceinline__ short f2bs(float f) {
    union { bf16 b; short s; } u; u.b = __float2bfloat16(f); return u.s;
}

// ---------------------------------------------------------------------------
// Proj body (shared by K2/K3): 32 nodes starting at node0, [xl|xr] =
// x @ [Wl;Wr]^T + bias via MFMA; epilogue through XOR-swizzled LDS tile
// (8 KB region passed in) -> coalesced bf16x8 stores.
// ---------------------------------------------------------------------------
static __device__ __forceinline__ void proj_body(
    int node0, short* lds,
    const float* __restrict__ xf, const float* __restrict__ xb,
    const float* __restrict__ Wl, const float* __restrict__ bl,
    const float* __restrict__ Wr, const float* __restrict__ br,
    const bf16* __restrict__ whi, const bf16* __restrict__ wlo,
    bf16* __restrict__ xl, bf16* __restrict__ xr)
{
    int wave = threadIdx.x >> 6;
    int lane = threadIdx.x & 63;
    int n = lane & 15, q = lane >> 4;

    bf16x8 bhi[2][4], blo_[2][4];
    float biasv[2], w128[2];
    #pragma unroll
    for (int nt = 0; nt < 2; ++nt) {
        int ch = wave * 32 + nt * 16 + n;
        #pragma unroll
        for (int ks = 0; ks < 4; ++ks) {
            int fid = wave * 8 + nt * 4 + ks;
            bhi[nt][ks]  = *(const bf16x8*)(whi + ((size_t)fid * 64 + lane) * 8);
            blo_[nt][ks] = *(const bf16x8*)(wlo + ((size_t)fid * 64 + lane) * 8);
        }
        biasv[nt] = (ch < 64) ? bl[ch] : br[ch - 64];
        w128[nt]  = (ch < 64) ? Wl[(size_t)ch * IN_DIM + 128]
                              : Wr[(size_t)(ch - 64) * IN_DIM + 128];
    }

    #pragma unroll
    for (int mt = 0; mt < 2; ++mt) {
        int nb = node0 + mt * 16;
        if (nb < N_NODES) {
            const float* xrow = xf + (size_t)(nb + n) * F_DIM;
            bf16x8 a[4];
            #pragma unroll
            for (int ks = 0; ks < 4; ++ks) {
                float4 u = *(const float4*)(xrow + ks * 32 + q * 8);
                float4 v = *(const float4*)(xrow + ks * 32 + q * 8 + 4);
                bf16x8 tt;
                tt[0] = f2bs(u.x); tt[1] = f2bs(u.y); tt[2] = f2bs(u.z); tt[3] = f2bs(u.w);
                tt[4] = f2bs(v.x); tt[5] = f2bs(v.y); tt[6] = f2bs(v.z); tt[7] = f2bs(v.w);
                a[ks] = tt;
            }
            f32x4 acc[2] = {{0.f,0.f,0.f,0.f},{0.f,0.f,0.f,0.f}};
            #pragma unroll
            for (int ks = 0; ks < 4; ++ks) {
                #pragma unroll
                for (int nt = 0; nt < 2; ++nt) {
                    acc[nt] = __builtin_amdgcn_mfma_f32_16x16x32_bf16(a[ks], bhi[nt][ks],  acc[nt], 0, 0, 0);
                    acc[nt] = __builtin_amdgcn_mfma_f32_16x16x32_bf16(a[ks], blo_[nt][ks], acc[nt], 0, 0, 0);
                }
            }
            float4 xbv = *(const float4*)(xb + nb + q * 4);
            float xbr[4] = {xbv.x, xbv.y, xbv.z, xbv.w};
            #pragma unroll
            for (int nt = 0; nt < 2; ++nt) {
                int ch = wave * 32 + nt * 16 + n;
                int blk = ch >> 3, pos = ch & 7;
                #pragma unroll
                for (int r = 0; r < 4; ++r) {
                    int nodeL = mt * 16 + q * 4 + r;   // C/D: row = quad*4 + reg
                    float val = acc[nt][r] + xbr[r] * w128[nt] + biasv[nt];
                    lds[nodeL * 128 + ((blk ^ (nodeL & 7)) << 3) + pos] = f2bs(val);
                }
            }
        }
    }
    __syncthreads();

    // Coalesced write-back: thread t -> node t>>3, 16B chunk t&7 of xl and xr.
    int nl = threadIdx.x >> 3, bk = threadIdx.x & 7;
    int node = node0 + nl;
    if (node < N_NODES) {
        bf16x8 v0 = *(const bf16x8*)(lds + nl * 128 + ((bk ^ (nl & 7)) << 3));
        *(bf16x8*)(xl + (size_t)node * H_DIM + bk * 8) = v0;
        bf16x8 v1 = *(const bf16x8*)(lds + nl * 128 + (((8 + bk) ^ (nl & 7)) << 3));
        *(bf16x8*)(xr + (size_t)node * H_DIM + bk * 8) = v1;
    }
}

// ---------------------------------------------------------------------------
// Prep: pack W (proj) and Wo (out) hi/lo MFMA B-fragments once, zero gtot.
// ---------------------------------------------------------------------------
__global__ __launch_bounds__(256) void prep_kernel(
    const float* __restrict__ Wl, const float* __restrict__ Wr,
    const float* __restrict__ Wo,
    bf16* __restrict__ whi, bf16* __restrict__ wlo,
    bf16* __restrict__ wohi, bf16* __restrict__ wolo,
    int* __restrict__ gtot)
{
    int b = blockIdx.x, t = threadIdx.x;
    if (b < 8) {                              // [Wl;Wr] frags: 2048 slots
        int s = b * 256 + t;
        int fid = s >> 6, l = s & 63;
        int wave = fid >> 3, nt = (fid >> 2) & 1, ks = fid & 3;
        int ch = wave * 32 + nt * 16 + (l & 15);
        int kb = ks * 32 + (l >> 4) * 8;
        const float* wrow = (ch < 64) ? Wl + (size_t)ch * IN_DIM
                                      : Wr + (size_t)(ch - 64) * IN_DIM;
        #pragma unroll
        for (int j = 0; j < 8; ++j) {
            float v = wrow[kb + j];
            short hs = f2bs(v);
            short ls = f2bs(v - bs2f(hs));
            ((short*)whi)[(size_t)s * 8 + j] = hs;
            ((short*)wlo)[(size_t)s * 8 + j] = ls;
        }
    } else if (b < 12) {                      // Wo frags: 1024 slots
        int s = (b - 8) * 256 + t;
        int fid = s >> 6, l = s & 63;
        int wave = fid >> 2, nt = (fid >> 1) & 1, ks = fid & 1;
        int ch = wave * 32 + nt * 16 + (l & 15);
        int kb = ks * 32 + (l >> 4) * 8;
        const float* wrow = Wo + (size_t)ch * H_DIM;
        #pragma unroll
        for (int j = 0; j < 8; ++j) {
            float v = wrow[kb + j];
            short hs = f2bs(v);
            short ls = f2bs(v - bs2f(hs));
            ((short*)wohi)[(size_t)s * 8 + j] = hs;
            ((short*)wolo)[(size_t)s * 8 + j] = ls;
        }
    } else {                                  // zero bucket totals
        if (t < NB) gtot[t] = 0;
    }
}

// ---------------------------------------------------------------------------
// K2 (hybrid): blocks [0,256) bucket sort level 1 (atomic-free placement);
// blocks [256, +PROJ_A) proj nodes [0, 25024).
// ---------------------------------------------------------------------------
__global__ __launch_bounds__(256) void h2_kernel(
    const float* __restrict__ xf, const float* __restrict__ xb,
    const float* __restrict__ Wl, const float* __restrict__ bl,
    const float* __restrict__ Wr, const float* __restrict__ br,
    const bf16* __restrict__ whi, const bf16* __restrict__ wlo,
    const int* __restrict__ esrc, const int* __restrict__ edst,
    bf16* __restrict__ xl, bf16* __restrict__ xr,
    int* __restrict__ gtot, unsigned* __restrict__ bstore2,
    int* __restrict__ bofsT)
{
    __shared__ int smem[2048];   // 8 KB, aliased per path

    if (blockIdx.x < BKT_BLKS) {
        // ---- bucket path (atomic-free placement) ----
        int* hist = smem;           // 196
        int* base = smem + 256;     // 196
        int* cur  = smem + 512;     // 196
        int* shs  = smem + 768;     // 256 scan temp
        int t = threadIdx.x;
        int b = blockIdx.x;
        int e0 = b * EPB;
        if (t < NB) hist[t] = 0;
        __syncthreads();

        int myd[13]; int mys[13];
        #pragma unroll
        for (int i = 0; i < 13; ++i) {       // 3125 = 12*256 + 53
            int k = t + i * 256;
            bool v = k < EPB;
            int dst = v ? edst[e0 + k] : -1;
            int sc  = v ? esrc[e0 + k] : 0;
            myd[i] = dst; mys[i] = sc;
            if (v) atomicAdd(&hist[dst >> 8], 1);     // LDS atomic
        }
        __syncthreads();

        int hv = (t < NB) ? hist[t] : 0;
        shs[t] = hv;
        __syncthreads();
        #pragma unroll
        for (int d = 1; d < 256; d <<= 1) {
            int x = (t >= d) ? shs[t - d] : 0;
            __syncthreads();
            shs[t] += x;
            __syncthreads();
        }
        if (t < NB) {
            int bs = shs[t] - hv;
            base[t] = bs;
            cur[t] = 0;
            if (hv) atomicAdd(&gtot[t], hv);          // non-returning global
            bofsT[t * 256 + b] = (bs << 16) | hv;     // packed (base,count)
        }
        __syncthreads();

        #pragma unroll
        for (int i = 0; i < 13; ++i) {
            if (myd[i] >= 0) {
                int j = myd[i] >> 8;
                int slot = base[j] + atomicAdd(&cur[j], 1);   // LDS atomic
                bstore2[(size_t)e0 + slot] =
                    ((unsigned)myd[i] << 16) | (unsigned)mys[i];
            }
        }
        return;
    }

    proj_body((blockIdx.x - BKT_BLKS) * 32, (short*)smem,
              xf, xb, Wl, bl, Wr, br, whi, wlo, xl, xr);
}

// ---------------------------------------------------------------------------
// K3 (hybrid): blocks [0,196) csr level 2 (one bucket each, 256 thr);
// blocks [196, +PROJ_B) proj nodes [25024, 50000).
// ---------------------------------------------------------------------------
__global__ __launch_bounds__(256) void h3_kernel(
    const float* __restrict__ xf, const float* __restrict__ xb,
    const float* __restrict__ Wl, const float* __restrict__ bl,
    const float* __restrict__ Wr, const float* __restrict__ br,
    const bf16* __restrict__ whi, const bf16* __restrict__ wlo,
    bf16* __restrict__ xl, bf16* __restrict__ xr,
    const int* __restrict__ gtot, const unsigned* __restrict__ bstore2,
    const int* __restrict__ bofsT,
    int* __restrict__ offs, int* __restrict__ csr_src)
{
    __shared__ int smem3[7176];   // 28.7 KB: ent[CAP] | sh | h256 | start | c2 | scal

    if (blockIdx.x < NB) {
        // ---- csr path ----
        unsigned* ent = (unsigned*)smem3;          // CAP
        int* sh    = smem3 + CAP;                  // 256
        int* h256  = smem3 + CAP + 256;            // 256
        int* start = smem3 + CAP + 512;            // 256
        int* c2    = smem3 + CAP + 768;            // 256
        int* scal  = smem3 + CAP + 1024;           // [0]=C, [1]=bb
        int j = blockIdx.x, t = threadIdx.x;

        unsigned v = (unsigned)bofsT[j * 256 + t];
        int bbase = (int)(v >> 16);
        int bcnt  = (int)(v & 0xffffu);
        sh[t] = bcnt;
        __syncthreads();
        #pragma unroll
        for (int d = 1; d < 256; d <<= 1) {
            int x = (t >= d) ? sh[t - d] : 0;
            __syncthreads();
            sh[t] += x;
            __syncthreads();
        }
        int gb = sh[t] - bcnt;
        if (t == 255) scal[0] = sh[255];
        __syncthreads();
        int C = scal[0];

        // gather this bucket's entries into LDS (per-thread source slice)
        {
            const unsigned* p = bstore2 + (size_t)t * EPB + bbase;
            for (int i = 0; i < bcnt; ++i) ent[gb + i] = p[i];
        }
        __syncthreads();

        // bucket-base prefix: val_j' = gtot[j'] + (real nodes in bucket j')
        int val = 0;
        if (t < NB) val = gtot[t] + ((t < NB - 1) ? 256 : (N_NODES - (NB - 1) * 256));
        sh[t] = val;
        __syncthreads();
        #pragma unroll
        for (int d = 1; d < 256; d <<= 1) {
            int x = (t >= d) ? sh[t - d] : 0;
            __syncthreads();
            sh[t] += x;
            __syncthreads();
        }
        if (t == j) scal[1] = sh[t] - val;     // exclusive prefix at own bucket
        h256[t] = 0;
        __syncthreads();
        int bb = scal[1];

        // 256-bin histogram over entries
        for (int k = t; k < C; k += 256)
            atomicAdd(&h256[(ent[k] >> 16) & 255], 1);   // LDS atomic
        __syncthreads();

        // scan of per-node widths (deg + 1 self-loop for real nodes)
        int node = j * 256 + t;
        int w = h256[t] + ((node < N_NODES) ? 1 : 0);
        sh[t] = w;
        __syncthreads();
        #pragma unroll
        for (int d = 1; d < 256; d <<= 1) {
            int x = (t >= d) ? sh[t - d] : 0;
            __syncthreads();
            sh[t] += x;
            __syncthreads();
        }
        int st = bb + sh[t] - w;
        start[t] = st;
        c2[t] = 0;
        if (node < N_NODES) {
            offs[node] = st;
            csr_src[st] = node;                 // self-loop at segment head
        }
        if (j == NB - 1 && t == 0) offs[N_NODES] = ETOT;   // sentinel
        __syncthreads();

        for (int k = t; k < C; k += 256) {
            unsigned en = ent[k];
            int bin = (en >> 16) & 255;
            int r = atomicAdd(&c2[bin], 1);     // LDS atomic
            csr_src[start[bin] + 1 + r] = (int)(en & 0xffffu);
        }
        return;
    }

    proj_body((PROJ_A + blockIdx.x - NB) * 32, (short*)smem3,
              xf, xb, Wl, bl, Wr, br, whi, wlo, xl, xr);
}

// ---------------------------------------------------------------------------
// K2b+K3 fused (agg_out): 16 dsts/block. NEW lane layout: each wave splits
// into 4x16-lane groups, ONE DST EACH (dl=lane>>4), g2=(lane>>3)&1 edge
// slot, c8=lane&7 channel octet. 4 independent depth-3 gather streams per
// wave at single-stream register cost (no A/B duplication); one pass (no
// sequential pair phases); acc/den combine is a single shfl_xor(8).
// Phase 2 (16-node out-MFMA tile) unchanged.
// ---------------------------------------------------------------------------
__global__ __launch_bounds__(256) void agg_out(
    const int* __restrict__ csr_src, const int* __restrict__ offs,
    const bf16* __restrict__ xl, const bf16* __restrict__ xr,
    const float* __restrict__ att, const float* __restrict__ gb,
    const bf16* __restrict__ wohi, const bf16* __restrict__ wolo,
    const float* __restrict__ bo, const float* __restrict__ disp,
    float* __restrict__ out)
{
    __shared__ short hts[16 * 72];     // h tile, rows padded to 144B
    __shared__ float ldso[16 * 132];   // out staging, +4 f32 row pad

    int wave = threadIdx.x >> 6;
    int lane = threadIdx.x & 63;
    int dl  = lane >> 4;         // dst slot within wave (0..3)
    int g2  = (lane >> 3) & 1;   // edge slot within batch (2/batch)
    int c8  = lane & 7;          // channel octet
    int wd  = wave * 4 + dl;     // local dst row 0..15
    int node0 = blockIdx.x * 16;
    int wid = node0 + wd;        // always < N_NODES (exact grid)

    if (blockIdx.x == 0 && threadIdx.x < F_DIM) {
        float d = disp[threadIdx.x];
        out[(size_t)N_NODES * F_DIM + threadIdx.x] = (d > 20.f) ? d : log1pf(__expf(d));
    }

    // hoisted per-lane constants (attv pre-scaled by log2e for exp2f)
    float attv[8], gbv[8];
    {
        float4 a0 = *(const float4*)(att + c8 * 8);
        float4 a1 = *(const float4*)(att + c8 * 8 + 4);
        const float L2E = 1.44269504f;
        attv[0] = a0.x * L2E; attv[1] = a0.y * L2E; attv[2] = a0.z * L2E; attv[3] = a0.w * L2E;
        attv[4] = a1.x * L2E; attv[5] = a1.y * L2E; attv[6] = a1.z * L2E; attv[7] = a1.w * L2E;
        float4 g0 = *(const float4*)(gb + c8 * 8);
        float4 g1 = *(const float4*)(gb + c8 * 8 + 4);
        gbv[0] = g0.x; gbv[1] = g0.y; gbv[2] = g0.z; gbv[3] = g0.w;
        gbv[4] = g1.x; gbv[5] = g1.y; gbv[6] = g1.z; gbv[7] = g1.w;
    }

    float xrv[8];
    {
        bf16x8 xrow = *(const bf16x8*)(xr + (size_t)wid * H_DIM + c8 * 8);
        #pragma unroll
        for (int j = 0; j < 8; ++j) xrv[j] = bs2f(xrow[j]);
    }

    int beg = offs[wid];
    int end = offs[wid + 1];     // >= beg+1 (self-loop)
    int last = end - 1;

    // wave-uniform iteration count: max over the wave's 4 dsts of
    // ceil((deg+1)/2). Lanes of a dst group agree; xor16/xor32 spread max.
    int nIt = (end - beg + 1) >> 1;
    nIt = max(nIt, __shfl_xor(nIt, 16));
    nIt = max(nIt, __shfl_xor(nIt, 32));

    float den = 0.f;
    float acc[8] = {0.f, 0.f, 0.f, 0.f, 0.f, 0.f, 0.f, 0.f};

    // depth-3 prologue: this lane's slots are beg + it*2 + g2
    int cur = beg + g2;
    int i0 = cur;     i0 = (i0 < end) ? i0 : last;
    int i1 = cur + 2; i1 = (i1 < end) ? i1 : last;
    int i2 = cur + 4; i2 = (i2 < end) ? i2 : last;
    int s2 = csr_src[i2];
    bf16x8 r0 = *(const bf16x8*)(xl + (size_t)csr_src[i0] * H_DIM + c8 * 8);
    bf16x8 r1 = *(const bf16x8*)(xl + (size_t)csr_src[i1] * H_DIM + c8 * 8);

    #pragma unroll 1
    for (int it = 0; it < nIt; ++it) {
        int i3 = cur + 6; i3 = (i3 < end) ? i3 : last;   // idx for it+3
        int s3 = csr_src[i3];
        bf16x8 r2 = *(const bf16x8*)(xl + (size_t)s2 * H_DIM + c8 * 8); // row it+2

        bool valid = cur < end;
        float xv[8], p = 0.f;
        #pragma unroll
        for (int j = 0; j < 8; ++j) {
            xv[j] = bs2f(r0[j]);
            float m = xv[j] + xrv[j];
            m = fmaxf(m, 0.2f * m);             // LeakyReLU
            p += m * attv[j];
        }
        p += __shfl_xor(p, 1);
        p += __shfl_xor(p, 2);
        p += __shfl_xor(p, 4);                  // 8 channel-lanes hold p
        float ex = valid ? exp2f(p) : 0.f;
        den += ex;
        #pragma unroll
        for (int j = 0; j < 8; ++j) acc[j] += ex * xv[j];

        r0 = r1; r1 = r2; s2 = s3; cur += 2;
    }

    // combine the two edge slots (g2) — single step
    #pragma unroll
    for (int j = 0; j < 8; ++j) acc[j] += __shfl_xor(acc[j], 8);
    den += __shfl_xor(den, 8);

    if (g2 == 0) {
        float inv = 1.0f / den;
        bf16x8 ov;
        #pragma unroll
        for (int j = 0; j < 8; ++j) {
            float v = acc[j] * inv + gbv[j];
            v = (v > 0.f) ? v : expm1f(v);
            ov[j] = f2bs(v);
        }
        *(bf16x8*)(hts + wd * 72 + c8 * 8) = ov;   // h row into LDS tile
    }
    __syncthreads();

    // ---- phase 2: 16-node out-MFMA tile (unchanged) ----
    int n = lane & 15, q = lane >> 4;

    bf16x8 bhi[2][2], blo_[2][2];
    float bov[2];
    #pragma unroll
    for (int nt = 0; nt < 2; ++nt) {
        int ch = wave * 32 + nt * 16 + n;
        #pragma unroll
        for (int ks = 0; ks < 2; ++ks) {
            int fid = wave * 4 + nt * 2 + ks;
            bhi[nt][ks]  = *(const bf16x8*)(wohi + ((size_t)fid * 64 + lane) * 8);
            blo_[nt][ks] = *(const bf16x8*)(wolo + ((size_t)fid * 64 + lane) * 8);
        }
        bov[nt] = bo[ch];
    }

    bf16x8 a[2];
    #pragma unroll
    for (int ks = 0; ks < 2; ++ks)
        a[ks] = *(const bf16x8*)(hts + n * 72 + ks * 32 + q * 8);
    f32x4 acc2[2] = {{0.f,0.f,0.f,0.f},{0.f,0.f,0.f,0.f}};
    #pragma unroll
    for (int ks = 0; ks < 2; ++ks) {
        #pragma unroll
        for (int nt = 0; nt < 2; ++nt) {
            acc2[nt] = __builtin_amdgcn_mfma_f32_16x16x32_bf16(a[ks], bhi[nt][ks],  acc2[nt], 0, 0, 0);
            acc2[nt] = __builtin_amdgcn_mfma_f32_16x16x32_bf16(a[ks], blo_[nt][ks], acc2[nt], 0, 0, 0);
        }
    }
    #pragma unroll
    for (int nt = 0; nt < 2; ++nt) {
        int ch = wave * 32 + nt * 16 + n;
        #pragma unroll
        for (int r = 0; r < 4; ++r) {
            int nodeL = q * 4 + r;         // C/D: row = quad*4 + reg
            ldso[nodeL * 132 + ch] = acc2[nt][r] + bov[nt];
        }
    }
    __syncthreads();

    // Coalesced write-back: thread t -> node t>>4, 32B part t&15.
    int nl = threadIdx.x >> 4, p = threadIdx.x & 15;
    const float* srcp = ldso + nl * 132 + p * 8;
    float* dstp = out + (size_t)(node0 + nl) * F_DIM + p * 8;
    *(float4*)(dstp)     = *(const float4*)(srcp);
    *(float4*)(dstp + 4) = *(const float4*)(srcp + 4);
}

// ---------------------------------------------------------------------------
extern "C" void kernel_launch(void* const* d_in, const int* in_sizes, int n_in,
                              void* d_out, int out_size, void* d_ws, size_t ws_size,
                              hipStream_t stream)
{
    const float* xf  = (const float*)d_in[0];
    const float* xb  = (const float*)d_in[1];
    const int*   ei  = (const int*)d_in[2];    // [2, E] int32, row-major
    const float* Wl  = (const float*)d_in[3];
    const float* bl  = (const float*)d_in[4];
    const float* Wr  = (const float*)d_in[5];
    const float* br  = (const float*)d_in[6];
    const float* att = (const float*)d_in[7];
    const float* gb  = (const float*)d_in[8];
    const float* Wo  = (const float*)d_in[9];
    const float* bo  = (const float*)d_in[10];
    const float* dp  = (const float*)d_in[11];
    float* out = (float*)d_out;
    const int* esrc = ei;
    const int* edst = ei + N_EDGES;

    // ws layout (16B-aligned segments):
    //  xl bf16[N*64] | xr bf16[N*64] | bstore2 u32[E] | csr_src int[ETOT] |
    //  offs int[N+4] | gtot int[208] | bofsT int[50176] | whi | wlo | wohi | wolo
    char* ws = (char*)d_ws;
    const size_t SZB = (size_t)N_NODES * H_DIM * sizeof(bf16);   // 6.4 MB
    bf16*  xl      = (bf16*)(ws);
    bf16*  xr      = (bf16*)(ws + SZB);
    unsigned* bstore2 = (unsigned*)(ws + 2 * SZB);
    int*   csr_src = (int*)(ws + 2 * SZB + (size_t)N_EDGES * 4);
    int*   offs    = csr_src + ETOT;
    int*   gtot    = offs + (N_NODES + 4);
    int*   bofsT   = gtot + 208;              // [196][256] packed (base<<16|cnt)
    bf16*  whi     = (bf16*)(bofsT + NB * 256);
    bf16*  wlo     = whi + 16384;
    bf16*  wohi    = wlo + 16384;
    bf16*  wolo    = wohi + 8192;

    prep_kernel<<<13, 256, 0, stream>>>(Wl, Wr, Wo, whi, wlo, wohi, wolo, gtot);

    h2_kernel<<<BKT_BLKS + PROJ_A, 256, 0, stream>>>(
        xf, xb, Wl, bl, Wr, br, whi, wlo, esrc, edst, xl, xr,
        gtot, bstore2, bofsT);

    h3_kernel<<<NB + PROJ_B, 256, 0, stream>>>(
        xf, xb, Wl, bl, Wr, br, whi, wlo, xl, xr,
        gtot, bstore2, bofsT, offs, csr_src);

    agg_out<<<AGG_BLKS, 256, 0, stream>>>(csr_src, offs, xl, xr, att, gb,
                                          wohi, wolo, bo, dp, out);
}